// Round 1
// baseline (544.804 us; speedup 1.0000x reference)
//
#include <hip/hip_runtime.h>
#include <hip/hip_bf16.h>
#include <hip/hip_fp16.h>

// GCN: 3 layers of  h = relu(in_norm * A_pull( (out_norm*x) @ W ) + b)
// then seg_output = (mean_n h3) @ Wp^T + bp  and  CAM = Wp @ h3^T.
// Preprocessing (R12): one count+rank pass, base-table scans, pure-streaming
// scatter, fused csr+outdeg+convw. No scattered global atomics.
// R13: XCD-sliced aggregation. All fp16 node-feature tensors stored as
// [8][N][16] feature slices (3.2 MB/slice < 4 MB per-XCD L2). agg grid =
// groups x 8 with slice = blockIdx.x & 7, so round-robin block->XCD dispatch
// pins each slice into one XCD's L2: the random row gather becomes L2-resident
// instead of 8x-replicated L3 fills (FETCH 179.5 MB -> ~85 MB predicted).
// Correctness does not depend on the dispatch mapping. CAM = MFMA GEMM
// (split-fp16 Wp, exact).

#define HDIM 128
#define NCLS 40
#define BSH 8
#define BSZ 256          // nodes per bucket
#define KMAX 512
#define NBMAX 512
#define EPB 4096         // edges per count/scatter block
#define CSTRIDE 140      // cam LDS row stride (fp16)

typedef _Float16 half8 __attribute__((ext_vector_type(8)));
typedef float f32x4 __attribute__((ext_vector_type(4)));

// sliced layout helper: feature chunk c8 (8 fp16) of node gr in [8][n][16]
__device__ __forceinline__ size_t sl_off(int gr, int c8, int n) {
    return ((size_t)(c8 >> 1)) * (size_t)n * 16 + (size_t)gr * 16 + (size_t)(c8 & 1) * 8;
}

// ---------------- graph preprocessing ----------------

__global__ void zero_kernel(int* __restrict__ p, int n) {
    int i = blockIdx.x * blockDim.x + threadIdx.x;
    if (i < n) p[i] = 0;
}

// One pass: LDS bucket histograms (dst+src), per-edge packed ranks,
// per-(bucket,block) count tables (k-major), global bucket totals.
__global__ __launch_bounds__(256) void count_rank_kernel(
        const int* __restrict__ src, const int* __restrict__ dst,
        int* __restrict__ bcnt, int* __restrict__ sbcnt,
        unsigned* __restrict__ rank, int* __restrict__ cntD, int* __restrict__ cntS,
        int K, int E) {
    __shared__ int lc[KMAX], ls[KMAX];
    const int tid = threadIdx.x;
    lc[tid] = 0; lc[tid + 256] = 0; ls[tid] = 0; ls[tid + 256] = 0;
    __syncthreads();
    const int base = blockIdx.x * EPB;
    const int lim = min(EPB, E - base);
    for (int i = tid; i < lim; i += 256) {
        int kd = dst[base + i] >> BSH, ks = src[base + i] >> BSH;
        unsigned rd = (unsigned)atomicAdd(&lc[kd], 1);
        unsigned rs = (unsigned)atomicAdd(&ls[ks], 1);
        rank[base + i] = rd | (rs << 16);
    }
    __syncthreads();
    for (int t = tid; t < K; t += 256) {
        cntD[t * NBMAX + blockIdx.x] = lc[t];
        cntS[t * NBMAX + blockIdx.x] = ls[t];
        if (lc[t]) atomicAdd(&bcnt[t], lc[t]);
        if (ls[t]) atomicAdd(&sbcnt[t], ls[t]);
    }
}

// one wave: exclusive scan of both bucket-total arrays (K <= KMAX)
__global__ void bucket_scan_kernel(const int* __restrict__ a, const int* __restrict__ b,
                                   int* __restrict__ abase, int* __restrict__ bbase, int K) {
    const int lane = threadIdx.x;   // blockDim = 64
    int ca = 0, cb = 0;
    for (int base = 0; base < K; base += 64) {
        int va = (base + lane < K) ? a[base + lane] : 0;
        int vb = (base + lane < K) ? b[base + lane] : 0;
        int ia = va, ib = vb;
        #pragma unroll
        for (int d = 1; d < 64; d <<= 1) {
            int oa = __shfl_up(ia, d, 64);
            int ob = __shfl_up(ib, d, 64);
            if (lane >= d) { ia += oa; ib += ob; }
        }
        if (base + lane < K) { abase[base + lane] = ca + ia - va; bbase[base + lane] = cb + ib - vb; }
        ca += __shfl(ia, 63, 64);
        cb += __shfl(ib, 63, 64);
    }
    if (lane == 0) { abase[K] = ca; bbase[K] = cb; }
}

// grid 2K x 64: convert count tables (k-major) to absolute base tables in place
__global__ void basebk_kernel(const int* __restrict__ bbase, const int* __restrict__ sbase,
                              int* __restrict__ cntD, int* __restrict__ cntS,
                              int K, int NB) {
    const bool isS = (int)blockIdx.x >= K;
    const int k = isS ? (blockIdx.x - K) : blockIdx.x;
    int* tbl = isS ? cntS : cntD;
    int run = isS ? sbase[k] : bbase[k];
    const int lane = threadIdx.x;   // 64
    for (int b0 = 0; b0 < NB; b0 += 64) {
        int v = (b0 + lane < NB) ? tbl[k * NBMAX + b0 + lane] : 0;
        int incl = v;
        #pragma unroll
        for (int d = 1; d < 64; d <<= 1) {
            int o = __shfl_up(incl, d, 64);
            if (lane >= d) incl += o;
        }
        if (b0 + lane < NB) tbl[k * NBMAX + b0 + lane] = run + incl - v;
        run += __shfl(incl, 63, 64);
    }
}

// pure streaming scatter: no LDS counting, no atomics
__global__ __launch_bounds__(256) void scatter_kernel(
        const int* __restrict__ src, const int* __restrict__ dst,
        const unsigned* __restrict__ rank,
        const int* __restrict__ baseD, const int* __restrict__ baseS,
        unsigned* __restrict__ dbuf, int* __restrict__ sbuf, int K, int E) {
    __shared__ int ldsD[KMAX], ldsS[KMAX];
    const int tid = threadIdx.x, b = blockIdx.x;
    for (int t = tid; t < K; t += 256) {
        ldsD[t] = baseD[t * NBMAX + b];
        ldsS[t] = baseS[t * NBMAX + b];
    }
    __syncthreads();
    const int base = b * EPB;
    const int lim = min(EPB, E - base);
    for (int i = tid; i < lim; i += 256) {
        int d = dst[base + i], s = src[base + i];
        unsigned r = rank[base + i];
        dbuf[ldsD[d >> BSH] + (r & 0xFFFFu)] = (unsigned)s | ((unsigned)(d & (BSZ - 1)) << 24);
        sbuf[ldsS[s >> BSH] + (r >> 16)] = s;
    }
}

// fused: blocks [0,K) build CSR; [K,2K) out_norm; [2K,..) weight conversion
__global__ __launch_bounds__(256) void finish_kernel(
        const unsigned* __restrict__ dbuf, const int* __restrict__ sbuf,
        const int* __restrict__ bbase, const int* __restrict__ sbase,
        int* __restrict__ row_ptr, float* __restrict__ in_norm,
        float* __restrict__ out_norm, int* __restrict__ col,
        const float* __restrict__ W1, const float* __restrict__ W2,
        const float* __restrict__ W3, const float* __restrict__ Wp,
        _Float16* __restrict__ WT, _Float16* __restrict__ Wph, _Float16* __restrict__ Wpr,
        int N, int K, int E) {
    __shared__ int cnt[BSZ], lsc[BSZ];
    __shared__ int wsum[4];
    const int blk = blockIdx.x, tid = threadIdx.x;

    if (blk < K) {
        // ---- build CSR for dst-bucket blk ----
        const int k = blk;
        const int node0 = k << BSH;
        const int beg = bbase[k], end = bbase[k + 1];
        cnt[tid] = 0;
        __syncthreads();
        for (int i = beg + tid; i < end; i += 256)
            atomicAdd(&cnt[dbuf[i] >> 24], 1);
        __syncthreads();
        const int c0 = cnt[tid];
        int incl = c0;
        const int lane = tid & 63, w = tid >> 6;
        #pragma unroll
        for (int d = 1; d < 64; d <<= 1) {
            int o = __shfl_up(incl, d, 64);
            if (lane >= d) incl += o;
        }
        if (lane == 63) wsum[w] = incl;
        __syncthreads();
        int off = 0;
        for (int j = 0; j < w; ++j) off += wsum[j];
        const int excl = off + incl - c0;
        lsc[tid] = excl;
        const int node = node0 + tid;
        if (node < N) { row_ptr[node] = beg + excl; in_norm[node] = 1.0f / sqrtf((float)max(c0, 1)); }
        if (k == K - 1 && tid == 0) row_ptr[N] = E;
        __syncthreads();
        cnt[tid] = 0;
        __syncthreads();
        for (int i = beg + tid; i < end; i += 256) {
            unsigned e = dbuf[i];
            int local = e >> 24;
            int r = atomicAdd(&cnt[local], 1);
            col[beg + lsc[local] + r] = (int)(e & 0xFFFFFFu);
        }
    } else if (blk < 2 * K) {
        // ---- out_norm for src-bucket blk-K ----
        const int k = blk - K;
        const int beg = sbase[k], end = sbase[k + 1];
        cnt[tid] = 0;
        __syncthreads();
        for (int i = beg + tid; i < end; i += 256)
            atomicAdd(&cnt[sbuf[i] & (BSZ - 1)], 1);
        __syncthreads();
        const int n0 = (k << BSH) + tid;
        if (n0 < N) out_norm[n0] = 1.0f / sqrtf((float)max(cnt[tid], 1));
    } else {
        // ---- weight conversion ----
        int i = (blk - 2 * K) * 256 + tid;
        if (i < 3 * HDIM * HDIM) {
            int w = i >> 14, r = i & (HDIM * HDIM - 1);
            int nn = r >> 7, kk = r & 127;
            const float* W = (w == 0) ? W1 : (w == 1) ? W2 : W3;
            WT[i] = (_Float16)W[kk * HDIM + nn];
        } else if (i < 3 * HDIM * HDIM + NCLS * HDIM) {
            int j = i - 3 * HDIM * HDIM;
            float v = Wp[j];
            _Float16 hi = (_Float16)v;
            Wph[j] = hi;
            Wpr[j] = (_Float16)(v - (float)hi);
        }
    }
}

// ---------------- dense compute ----------------

// out[m,:] = fp16( (out_norm[m]*x[m,:]) @ W ) via mfma_f32_16x16x32_f16.
// 128-row block, 2 m-tiles/wave; fp16 LDS staging; IT = float (row-major
// input) or _Float16 (sliced input). Output always sliced [8][n][16].
template <typename IT>
__global__ __launch_bounds__(256) void gemm_mfma_kernel(
        const IT* __restrict__ x, const _Float16* __restrict__ WT,
        const float* __restrict__ out_norm, _Float16* __restrict__ out, int n) {
    __shared__ _Float16 xh[128 * 136];          // 34.8 KB; also epilogue cs
    const int tid = threadIdx.x;
    const int wave = tid >> 6, lane = tid & 63;
    const int quad = lane >> 4, cI = lane & 15;
    const int row0 = blockIdx.x * 128;

    for (int t = tid; t < 128 * 16; t += 256) {
        int r = t >> 4, c8 = t & 15;
        int gr = row0 + r;
        half8 hv = {};
        if (gr < n) {
            float sc = out_norm[gr];
            if constexpr (sizeof(IT) == 2) {
                half8 v = *(const half8*)((const _Float16*)x + sl_off(gr, c8, n));
                #pragma unroll
                for (int q = 0; q < 8; ++q) hv[q] = (_Float16)((float)v[q] * sc);
            } else {
                const float* xr = (const float*)x + (size_t)gr * HDIM + c8 * 8;
                float4 u = *(const float4*)xr;
                float4 v = *(const float4*)(xr + 4);
                hv[0] = (_Float16)(u.x * sc); hv[1] = (_Float16)(u.y * sc);
                hv[2] = (_Float16)(u.z * sc); hv[3] = (_Float16)(u.w * sc);
                hv[4] = (_Float16)(v.x * sc); hv[5] = (_Float16)(v.y * sc);
                hv[6] = (_Float16)(v.z * sc); hv[7] = (_Float16)(v.w * sc);
            }
        }
        *(half8*)&xh[r * 136 + c8 * 8] = hv;
    }
    __syncthreads();

    half8 afr[2][4];
    #pragma unroll
    for (int i = 0; i < 2; ++i) {
        int mrow = wave * 32 + i * 16 + cI;
        #pragma unroll
        for (int kc = 0; kc < 4; ++kc)
            afr[i][kc] = *(const half8*)&xh[mrow * 136 + kc * 32 + quad * 8];
    }
    __syncthreads();

    f32x4 acc[2][8];
    #pragma unroll
    for (int i = 0; i < 2; ++i)
        #pragma unroll
        for (int nt = 0; nt < 8; ++nt) acc[i][nt] = (f32x4){0.f, 0.f, 0.f, 0.f};

    #pragma unroll
    for (int nt = 0; nt < 8; ++nt) {
        const _Float16* wb = WT + (size_t)(nt * 16 + cI) * HDIM + quad * 8;
        half8 bfr[4];
        #pragma unroll
        for (int kc = 0; kc < 4; ++kc) bfr[kc] = *(const half8*)(wb + kc * 32);
        #pragma unroll
        for (int i = 0; i < 2; ++i)
            #pragma unroll
            for (int kc = 0; kc < 4; ++kc)
                acc[i][nt] = __builtin_amdgcn_mfma_f32_16x16x32_f16(afr[i][kc], bfr[kc], acc[i][nt], 0, 0, 0);
    }

    _Float16 (*cs)[136] = (_Float16(*)[136])xh;
    #pragma unroll
    for (int i = 0; i < 2; ++i)
        #pragma unroll
        for (int nt = 0; nt < 8; ++nt)
            #pragma unroll
            for (int r = 0; r < 4; ++r)
                cs[wave * 32 + i * 16 + quad * 4 + r][nt * 16 + cI] = (_Float16)acc[i][nt][r];
    __syncthreads();

    for (int t = tid; t < 128 * 16; t += 256) {
        int r = t >> 4, c8 = t & 15;
        int gr = row0 + r;
        if (gr < n)
            *(float4*)(out + sl_off(gr, c8, n)) = *(float4*)&cs[r][c8 * 8];
    }
}

// XCD-sliced gather: block (g, s=blockIdx&7) aggregates feature slice s
// (16 feats, 32 B/row) for 16 nodes. Round-robin dispatch pins slice s to
// XCD s, so the 3.2 MB slice stays L2-resident. 16 lanes/node =
// 8 edge-slots x 2 chunks; fp32 accumulate; shfl_xor slot reduction.
__global__ __launch_bounds__(256) void agg_slice_kernel(
        const _Float16* __restrict__ t, const int* __restrict__ row_ptr,
        const int* __restrict__ col, const float* __restrict__ in_norm,
        const float* __restrict__ bias, _Float16* __restrict__ h, int n) {
    const int s = blockIdx.x & 7;           // slice == XCD under round-robin
    const int g = blockIdx.x >> 3;
    const int tid = threadIdx.x;
    int node = g * 16 + (tid >> 4);
    const bool live = node < n;
    if (!live) node = n - 1;                // keep whole group active for shfl
    const int L = tid & 15;                 // lane within 16-lane node group
    const int slot = L >> 1, chunk = L & 1;
    const int lane = tid & 63;
    const int gb = lane & 48;               // node-group base within wave

    const _Float16* ts = t + (size_t)s * (size_t)n * 16;
    const int beg = row_ptr[node], end = row_ptr[node + 1];
    float f[8] = {};
    for (int e = beg; e < end; e += 16) {
        const int cnt = min(16, end - e);
        int ci = (L < cnt) ? col[e + L] : 0;
        #pragma unroll
        for (int j = 0; j < 2; ++j) {
            const int idx = j * 8 + slot;
            int sc = __shfl(ci, gb + idx, 64);
            half8 v = {};
            if (idx < cnt) v = *(const half8*)(ts + (size_t)sc * 16 + chunk * 8);
            #pragma unroll
            for (int q = 0; q < 8; ++q) f[q] += (float)v[q];
        }
    }
    #pragma unroll
    for (int m = 2; m <= 8; m <<= 1)
        #pragma unroll
        for (int q = 0; q < 8; ++q) f[q] += __shfl_xor(f[q], m, 64);

    if (slot == 0 && live) {
        const float inn = in_norm[node];
        const float* bp = bias + s * 16 + chunk * 8;
        float4 b0 = *(const float4*)bp;
        float4 b1 = *(const float4*)(bp + 4);
        half8 hv;
        hv[0] = (_Float16)fmaxf(f[0] * inn + b0.x, 0.f);
        hv[1] = (_Float16)fmaxf(f[1] * inn + b0.y, 0.f);
        hv[2] = (_Float16)fmaxf(f[2] * inn + b0.z, 0.f);
        hv[3] = (_Float16)fmaxf(f[3] * inn + b0.w, 0.f);
        hv[4] = (_Float16)fmaxf(f[4] * inn + b1.x, 0.f);
        hv[5] = (_Float16)fmaxf(f[5] * inn + b1.y, 0.f);
        hv[6] = (_Float16)fmaxf(f[6] * inn + b1.z, 0.f);
        hv[7] = (_Float16)fmaxf(f[7] * inn + b1.w, 0.f);
        *(half8*)(h + (size_t)s * (size_t)n * 16 + (size_t)node * 16 + chunk * 8) = hv;
    }
}

__global__ void seg_kernel(const float* __restrict__ colsum, const float* __restrict__ Wp,
                           const float* __restrict__ bp, float* __restrict__ segout, float inv_n) {
    int c = threadIdx.x;
    if (c < NCLS) {
        float s = 0.f;
        #pragma unroll 4
        for (int k = 0; k < HDIM; ++k) s = fmaf(colsum[k], Wp[c * HDIM + k], s);
        segout[c] = s * inv_n + bp[c];
    }
}

// CAM via MFMA: CAM[c,n] = dot(Wp[c,:], h3[n,:]). h3 is sliced [8][n][16].
// Block = 128 nodes staged in LDS; per class-tile A load.
__global__ __launch_bounds__(256) void cam_mfma_kernel(
        const _Float16* __restrict__ h, const _Float16* __restrict__ Wph,
        const _Float16* __restrict__ Wpr, float* __restrict__ out,
        float* __restrict__ colsum, int n) {
    __shared__ _Float16 hs[128 * CSTRIDE];      // 35 KB
    const int tid = threadIdx.x;
    const int wave = tid >> 6, lane = tid & 63;
    const int quad = lane >> 4, cI = lane & 15;
    const int n0 = blockIdx.x * 128;

    for (int t = tid; t < 128 * 16; t += 256) {
        int r = t >> 4, c8 = t & 15;
        int gr = n0 + r;
        half8 v = {};
        if (gr < n) v = *(const half8*)(h + sl_off(gr, c8, n));
        *(half8*)&hs[r * CSTRIDE + c8 * 8] = v;
    }
    __syncthreads();

    #pragma unroll
    for (int ct = 0; ct < 3; ++ct) {
        const int cls = ct * 16 + cI;
        const bool av = cls < NCLS;
        const int clc = av ? cls : 0;
        half8 ah[4], ar[4];
        #pragma unroll
        for (int kc = 0; kc < 4; ++kc) {
            half8 z = {};
            half8 vh = *(const half8*)(Wph + clc * HDIM + kc * 32 + quad * 8);
            half8 vr = *(const half8*)(Wpr + clc * HDIM + kc * 32 + quad * 8);
            ah[kc] = av ? vh : z;
            ar[kc] = av ? vr : z;
        }
        #pragma unroll
        for (int t = 0; t < 2; ++t) {
            const int ln = wave * 32 + t * 16 + cI;
            f32x4 acc = (f32x4){0.f, 0.f, 0.f, 0.f};
            #pragma unroll
            for (int kc = 0; kc < 4; ++kc) {
                half8 b = *(const half8*)&hs[ln * CSTRIDE + kc * 32 + quad * 8];
                acc = __builtin_amdgcn_mfma_f32_16x16x32_f16(ah[kc], b, acc, 0, 0, 0);
                acc = __builtin_amdgcn_mfma_f32_16x16x32_f16(ar[kc], b, acc, 0, 0, 0);
            }
            const int node = n0 + ln;
            #pragma unroll
            for (int r = 0; r < 4; ++r) {
                int c2 = ct * 16 + quad * 4 + r;
                if (c2 < NCLS && node < n)
                    out[(size_t)c2 * n + node] = acc[r];
            }
        }
    }

    if (tid < HDIM) {
        float s = 0.f;
        for (int r = 0; r < 128; ++r) s += (float)hs[r * CSTRIDE + tid];
        atomicAdd(&colsum[tid], s);
    }
}

// ---------------- launch ----------------

extern "C" void kernel_launch(void* const* d_in, const int* in_sizes, int n_in,
                              void* d_out, int out_size, void* d_ws, size_t ws_size,
                              hipStream_t stream) {
    const float* features = (const float*)d_in[0];
    const float* W1 = (const float*)d_in[1];
    const float* b1 = (const float*)d_in[2];
    const float* W2 = (const float*)d_in[3];
    const float* b2 = (const float*)d_in[4];
    const float* W3 = (const float*)d_in[5];
    const float* b3 = (const float*)d_in[6];
    const float* Wp = (const float*)d_in[7];
    const float* bp = (const float*)d_in[8];
    const int*   src = (const int*)d_in[9];
    const int*   dst = (const int*)d_in[10];

    const int N = in_sizes[0] / HDIM;
    const int E = in_sizes[9];
    const int K = (N + BSZ - 1) >> BSH;           // buckets (<= KMAX)
    const int NB = (E + EPB - 1) / EPB;           // <= NBMAX
    float* out = (float*)d_out;

    // workspace carve-up
    char* ws = (char*)d_ws;
    size_t off = 0;
    int* bcnt   = (int*)(ws + off); off += KMAX * 4;
    int* sbcnt  = (int*)(ws + off); off += KMAX * 4;
    float* colsum = (float*)(ws + off); off += 128 * 4;
    int* bbase  = (int*)(ws + off); off += (KMAX + 1) * 4;
    int* sbase  = (int*)(ws + off); off += (KMAX + 1) * 4;
    int* cntD   = (int*)(ws + off); off += (size_t)KMAX * NBMAX * 4;   // -> baseD
    int* cntS   = (int*)(ws + off); off += (size_t)KMAX * NBMAX * 4;   // -> baseS
    int* row_ptr = (int*)(ws + off); off += ((size_t)N + 1) * 4; off = (off + 15) & ~(size_t)15;
    int* col_idx = (int*)(ws + off); off += (size_t)E * 4; off = (off + 15) & ~(size_t)15;
    float* out_norm = (float*)(ws + off); off += (size_t)N * 4;
    float* in_norm  = (float*)(ws + off); off += (size_t)N * 4; off = (off + 255) & ~(size_t)255;
    _Float16* WT  = (_Float16*)(ws + off); off += 3 * HDIM * HDIM * 2;
    _Float16* Wph = (_Float16*)(ws + off); off += NCLS * HDIM * 2;
    _Float16* Wpr = (_Float16*)(ws + off); off += NCLS * HDIM * 2; off = (off + 255) & ~(size_t)255;
    _Float16* Bh  = (_Float16*)(ws + off); off += (size_t)N * HDIM * 2; off = (off + 255) & ~(size_t)255;
    _Float16* F0h = (_Float16*)(ws + off); off += (size_t)N * HDIM * 2; off = (off + 255) & ~(size_t)255;
    (void)ws_size; (void)n_in; (void)out_size;

    // aliases: rank in Bh (first written by gemm1); dbuf/sbuf in F0h (first
    // written by agg1, after finish_kernel consumed them)
    unsigned* rank = (unsigned*)Bh;                   // E*4 B
    unsigned* dbuf = (unsigned*)F0h;                  // E*4 B (packed src|local<<24)
    int*      sbuf = (int*)((char*)F0h + (size_t)E * 4);  // E*4 B

    const int nzero = 2 * KMAX + 128;
    zero_kernel<<<(nzero + 255) / 256, 256, 0, stream>>>((int*)ws, nzero);
    count_rank_kernel<<<NB, 256, 0, stream>>>(src, dst, bcnt, sbcnt, rank, cntD, cntS, K, E);
    bucket_scan_kernel<<<1, 64, 0, stream>>>(bcnt, sbcnt, bbase, sbase, K);
    basebk_kernel<<<2 * K, 64, 0, stream>>>(bbase, sbase, cntD, cntS, K, NB);
    scatter_kernel<<<NB, 256, 0, stream>>>(src, dst, rank, cntD, cntS, dbuf, sbuf, K, E);

    const int conv_blocks = (3 * HDIM * HDIM + NCLS * HDIM + 255) / 256;
    finish_kernel<<<2 * K + conv_blocks, 256, 0, stream>>>(
        dbuf, sbuf, bbase, sbase, row_ptr, in_norm, out_norm, col_idx,
        W1, W2, W3, Wp, WT, Wph, Wpr, N, K, E);

    const int gemm_blocks = (N + 127) / 128;
    const int agg_blocks  = ((N + 15) / 16) * 8;     // node-groups x 8 slices

    // layer 1
    gemm_mfma_kernel<float><<<gemm_blocks, 256, 0, stream>>>(features, WT, out_norm, Bh, N);
    agg_slice_kernel<<<agg_blocks, 256, 0, stream>>>(Bh, row_ptr, col_idx, in_norm, b1, F0h, N);
    // layer 2
    gemm_mfma_kernel<_Float16><<<gemm_blocks, 256, 0, stream>>>(F0h, WT + HDIM * HDIM, out_norm, Bh, N);
    agg_slice_kernel<<<agg_blocks, 256, 0, stream>>>(Bh, row_ptr, col_idx, in_norm, b2, F0h, N);
    // layer 3 (h3 sliced fp16 -> F0h)
    gemm_mfma_kernel<_Float16><<<gemm_blocks, 256, 0, stream>>>(F0h, WT + 2 * HDIM * HDIM, out_norm, Bh, N);
    agg_slice_kernel<<<agg_blocks, 256, 0, stream>>>(Bh, row_ptr, col_idx, in_norm, b3, F0h, N);

    // head: cam (MFMA, fused colsum) then seg
    cam_mfma_kernel<<<(N + 127) / 128, 256, 0, stream>>>(F0h, Wph, Wpr, out + NCLS, colsum, N);
    seg_kernel<<<1, 64, 0, stream>>>(colsum, Wp, bp, out, 1.0f / (float)N);
}

// Round 3
// 544.153 us; speedup vs baseline: 1.0012x; 1.0012x over previous
//
#include <hip/hip_runtime.h>
#include <hip/hip_bf16.h>
#include <hip/hip_fp16.h>

// GCN: 3 layers of  h = relu(in_norm * A_pull( (out_norm*x) @ W ) + b)
// then seg_output = (mean_n h3) @ Wp^T + bp  and  CAM = Wp @ h3^T.
// Preprocessing (R12): one count+rank pass, base-table scans, pure-streaming
// scatter, fused csr+outdeg+convw. No scattered global atomics.
// R13: XCD-sliced fp16 tensors [8][N][16] (3.2 MB/slice < 4 MB per-XCD L2);
// agg grid = groups x 8, slice = blockIdx&7 -> round-robin dispatch pins each
// slice into one XCD's L2. Measured: FETCH 179.5 -> 44 MB. But the 16-lane
// gather shape was instruction-bound (92 us, VALUBusy 71%, deg~16 makes
// fixed costs dominate).
// R14: gather rebuilt for deg~16: 4 lanes/node (2 slots x 2 chunks), serial
// edge walk w/ unroll-2, direct col loads (no shfl chain), 32-bit slice
// addressing (saddr loads), v_dot2_f32_f16 accumulate (1 instr per fp16
// into f32, exact), single shfl_xor reduction round.
// R15: compile fix — __builtin_shufflevector needs literal indices;
// hand-unrolled accum8.

#define HDIM 128
#define NCLS 40
#define BSH 8
#define BSZ 256          // nodes per bucket
#define KMAX 512
#define NBMAX 512
#define EPB 4096         // edges per count/scatter block
#define CSTRIDE 140      // cam LDS row stride (fp16)

typedef _Float16 half8 __attribute__((ext_vector_type(8)));
typedef _Float16 half2t __attribute__((ext_vector_type(2)));
typedef float f32x4 __attribute__((ext_vector_type(4)));

// sliced layout helper: feature chunk c8 (8 fp16) of node gr in [8][n][16]
__device__ __forceinline__ size_t sl_off(int gr, int c8, int n) {
    return ((size_t)(c8 >> 1)) * (size_t)n * 16 + (size_t)gr * 16 + (size_t)(c8 & 1) * 8;
}

// accumulate 8 fp16 into 8 f32 sums; fdot2 = 1 VALU per element, exact
__device__ __forceinline__ void accum8(float* f, half8 v) {
#if __has_builtin(__builtin_amdgcn_fdot2)
    const half2t m0 = {(_Float16)1.0f, (_Float16)0.0f};
    const half2t m1 = {(_Float16)0.0f, (_Float16)1.0f};
    half2t a0 = __builtin_shufflevector(v, v, 0, 1);
    half2t a1 = __builtin_shufflevector(v, v, 2, 3);
    half2t a2 = __builtin_shufflevector(v, v, 4, 5);
    half2t a3 = __builtin_shufflevector(v, v, 6, 7);
    f[0] = __builtin_amdgcn_fdot2(a0, m0, f[0], false);
    f[1] = __builtin_amdgcn_fdot2(a0, m1, f[1], false);
    f[2] = __builtin_amdgcn_fdot2(a1, m0, f[2], false);
    f[3] = __builtin_amdgcn_fdot2(a1, m1, f[3], false);
    f[4] = __builtin_amdgcn_fdot2(a2, m0, f[4], false);
    f[5] = __builtin_amdgcn_fdot2(a2, m1, f[5], false);
    f[6] = __builtin_amdgcn_fdot2(a3, m0, f[6], false);
    f[7] = __builtin_amdgcn_fdot2(a3, m1, f[7], false);
#else
    #pragma unroll
    for (int q = 0; q < 8; ++q) f[q] += (float)v[q];
#endif
}

// ---------------- graph preprocessing ----------------

__global__ void zero_kernel(int* __restrict__ p, int n) {
    int i = blockIdx.x * blockDim.x + threadIdx.x;
    if (i < n) p[i] = 0;
}

// One pass: LDS bucket histograms (dst+src), per-edge packed ranks,
// per-(bucket,block) count tables (k-major), global bucket totals.
__global__ __launch_bounds__(256) void count_rank_kernel(
        const int* __restrict__ src, const int* __restrict__ dst,
        int* __restrict__ bcnt, int* __restrict__ sbcnt,
        unsigned* __restrict__ rank, int* __restrict__ cntD, int* __restrict__ cntS,
        int K, int E) {
    __shared__ int lc[KMAX], ls[KMAX];
    const int tid = threadIdx.x;
    lc[tid] = 0; lc[tid + 256] = 0; ls[tid] = 0; ls[tid + 256] = 0;
    __syncthreads();
    const int base = blockIdx.x * EPB;
    const int lim = min(EPB, E - base);
    for (int i = tid; i < lim; i += 256) {
        int kd = dst[base + i] >> BSH, ks = src[base + i] >> BSH;
        unsigned rd = (unsigned)atomicAdd(&lc[kd], 1);
        unsigned rs = (unsigned)atomicAdd(&ls[ks], 1);
        rank[base + i] = rd | (rs << 16);
    }
    __syncthreads();
    for (int t = tid; t < K; t += 256) {
        cntD[t * NBMAX + blockIdx.x] = lc[t];
        cntS[t * NBMAX + blockIdx.x] = ls[t];
        if (lc[t]) atomicAdd(&bcnt[t], lc[t]);
        if (ls[t]) atomicAdd(&sbcnt[t], ls[t]);
    }
}

// one wave: exclusive scan of both bucket-total arrays (K <= KMAX)
__global__ void bucket_scan_kernel(const int* __restrict__ a, const int* __restrict__ b,
                                   int* __restrict__ abase, int* __restrict__ bbase, int K) {
    const int lane = threadIdx.x;   // blockDim = 64
    int ca = 0, cb = 0;
    for (int base = 0; base < K; base += 64) {
        int va = (base + lane < K) ? a[base + lane] : 0;
        int vb = (base + lane < K) ? b[base + lane] : 0;
        int ia = va, ib = vb;
        #pragma unroll
        for (int d = 1; d < 64; d <<= 1) {
            int oa = __shfl_up(ia, d, 64);
            int ob = __shfl_up(ib, d, 64);
            if (lane >= d) { ia += oa; ib += ob; }
        }
        if (base + lane < K) { abase[base + lane] = ca + ia - va; bbase[base + lane] = cb + ib - vb; }
        ca += __shfl(ia, 63, 64);
        cb += __shfl(ib, 63, 64);
    }
    if (lane == 0) { abase[K] = ca; bbase[K] = cb; }
}

// grid 2K x 64: convert count tables (k-major) to absolute base tables in place
__global__ void basebk_kernel(const int* __restrict__ bbase, const int* __restrict__ sbase,
                              int* __restrict__ cntD, int* __restrict__ cntS,
                              int K, int NB) {
    const bool isS = (int)blockIdx.x >= K;
    const int k = isS ? (blockIdx.x - K) : blockIdx.x;
    int* tbl = isS ? cntS : cntD;
    int run = isS ? sbase[k] : bbase[k];
    const int lane = threadIdx.x;   // 64
    for (int b0 = 0; b0 < NB; b0 += 64) {
        int v = (b0 + lane < NB) ? tbl[k * NBMAX + b0 + lane] : 0;
        int incl = v;
        #pragma unroll
        for (int d = 1; d < 64; d <<= 1) {
            int o = __shfl_up(incl, d, 64);
            if (lane >= d) incl += o;
        }
        if (b0 + lane < NB) tbl[k * NBMAX + b0 + lane] = run + incl - v;
        run += __shfl(incl, 63, 64);
    }
}

// pure streaming scatter: no LDS counting, no atomics
__global__ __launch_bounds__(256) void scatter_kernel(
        const int* __restrict__ src, const int* __restrict__ dst,
        const unsigned* __restrict__ rank,
        const int* __restrict__ baseD, const int* __restrict__ baseS,
        unsigned* __restrict__ dbuf, int* __restrict__ sbuf, int K, int E) {
    __shared__ int ldsD[KMAX], ldsS[KMAX];
    const int tid = threadIdx.x, b = blockIdx.x;
    for (int t = tid; t < K; t += 256) {
        ldsD[t] = baseD[t * NBMAX + b];
        ldsS[t] = baseS[t * NBMAX + b];
    }
    __syncthreads();
    const int base = b * EPB;
    const int lim = min(EPB, E - base);
    for (int i = tid; i < lim; i += 256) {
        int d = dst[base + i], s = src[base + i];
        unsigned r = rank[base + i];
        dbuf[ldsD[d >> BSH] + (r & 0xFFFFu)] = (unsigned)s | ((unsigned)(d & (BSZ - 1)) << 24);
        sbuf[ldsS[s >> BSH] + (r >> 16)] = s;
    }
}

// fused: blocks [0,K) build CSR; [K,2K) out_norm; [2K,..) weight conversion
__global__ __launch_bounds__(256) void finish_kernel(
        const unsigned* __restrict__ dbuf, const int* __restrict__ sbuf,
        const int* __restrict__ bbase, const int* __restrict__ sbase,
        int* __restrict__ row_ptr, float* __restrict__ in_norm,
        float* __restrict__ out_norm, int* __restrict__ col,
        const float* __restrict__ W1, const float* __restrict__ W2,
        const float* __restrict__ W3, const float* __restrict__ Wp,
        _Float16* __restrict__ WT, _Float16* __restrict__ Wph, _Float16* __restrict__ Wpr,
        int N, int K, int E) {
    __shared__ int cnt[BSZ], lsc[BSZ];
    __shared__ int wsum[4];
    const int blk = blockIdx.x, tid = threadIdx.x;

    if (blk < K) {
        // ---- build CSR for dst-bucket blk ----
        const int k = blk;
        const int node0 = k << BSH;
        const int beg = bbase[k], end = bbase[k + 1];
        cnt[tid] = 0;
        __syncthreads();
        for (int i = beg + tid; i < end; i += 256)
            atomicAdd(&cnt[dbuf[i] >> 24], 1);
        __syncthreads();
        const int c0 = cnt[tid];
        int incl = c0;
        const int lane = tid & 63, w = tid >> 6;
        #pragma unroll
        for (int d = 1; d < 64; d <<= 1) {
            int o = __shfl_up(incl, d, 64);
            if (lane >= d) incl += o;
        }
        if (lane == 63) wsum[w] = incl;
        __syncthreads();
        int off = 0;
        for (int j = 0; j < w; ++j) off += wsum[j];
        const int excl = off + incl - c0;
        lsc[tid] = excl;
        const int node = node0 + tid;
        if (node < N) { row_ptr[node] = beg + excl; in_norm[node] = 1.0f / sqrtf((float)max(c0, 1)); }
        if (k == K - 1 && tid == 0) row_ptr[N] = E;
        __syncthreads();
        cnt[tid] = 0;
        __syncthreads();
        for (int i = beg + tid; i < end; i += 256) {
            unsigned e = dbuf[i];
            int local = e >> 24;
            int r = atomicAdd(&cnt[local], 1);
            col[beg + lsc[local] + r] = (int)(e & 0xFFFFFFu);
        }
    } else if (blk < 2 * K) {
        // ---- out_norm for src-bucket blk-K ----
        const int k = blk - K;
        const int beg = sbase[k], end = sbase[k + 1];
        cnt[tid] = 0;
        __syncthreads();
        for (int i = beg + tid; i < end; i += 256)
            atomicAdd(&cnt[sbuf[i] & (BSZ - 1)], 1);
        __syncthreads();
        const int n0 = (k << BSH) + tid;
        if (n0 < N) out_norm[n0] = 1.0f / sqrtf((float)max(cnt[tid], 1));
    } else {
        // ---- weight conversion ----
        int i = (blk - 2 * K) * 256 + tid;
        if (i < 3 * HDIM * HDIM) {
            int w = i >> 14, r = i & (HDIM * HDIM - 1);
            int nn = r >> 7, kk = r & 127;
            const float* W = (w == 0) ? W1 : (w == 1) ? W2 : W3;
            WT[i] = (_Float16)W[kk * HDIM + nn];
        } else if (i < 3 * HDIM * HDIM + NCLS * HDIM) {
            int j = i - 3 * HDIM * HDIM;
            float v = Wp[j];
            _Float16 hi = (_Float16)v;
            Wph[j] = hi;
            Wpr[j] = (_Float16)(v - (float)hi);
        }
    }
}

// ---------------- dense compute ----------------

// out[m,:] = fp16( (out_norm[m]*x[m,:]) @ W ) via mfma_f32_16x16x32_f16.
// 128-row block, 2 m-tiles/wave; fp16 LDS staging; IT = float (row-major
// input) or _Float16 (sliced input). Output always sliced [8][n][16].
template <typename IT>
__global__ __launch_bounds__(256) void gemm_mfma_kernel(
        const IT* __restrict__ x, const _Float16* __restrict__ WT,
        const float* __restrict__ out_norm, _Float16* __restrict__ out, int n) {
    __shared__ _Float16 xh[128 * 136];          // 34.8 KB; also epilogue cs
    const int tid = threadIdx.x;
    const int wave = tid >> 6, lane = tid & 63;
    const int quad = lane >> 4, cI = lane & 15;
    const int row0 = blockIdx.x * 128;

    for (int t = tid; t < 128 * 16; t += 256) {
        int r = t >> 4, c8 = t & 15;
        int gr = row0 + r;
        half8 hv = {};
        if (gr < n) {
            float sc = out_norm[gr];
            if constexpr (sizeof(IT) == 2) {
                half8 v = *(const half8*)((const _Float16*)x + sl_off(gr, c8, n));
                #pragma unroll
                for (int q = 0; q < 8; ++q) hv[q] = (_Float16)((float)v[q] * sc);
            } else {
                const float* xr = (const float*)x + (size_t)gr * HDIM + c8 * 8;
                float4 u = *(const float4*)xr;
                float4 v = *(const float4*)(xr + 4);
                hv[0] = (_Float16)(u.x * sc); hv[1] = (_Float16)(u.y * sc);
                hv[2] = (_Float16)(u.z * sc); hv[3] = (_Float16)(u.w * sc);
                hv[4] = (_Float16)(v.x * sc); hv[5] = (_Float16)(v.y * sc);
                hv[6] = (_Float16)(v.z * sc); hv[7] = (_Float16)(v.w * sc);
            }
        }
        *(half8*)&xh[r * 136 + c8 * 8] = hv;
    }
    __syncthreads();

    half8 afr[2][4];
    #pragma unroll
    for (int i = 0; i < 2; ++i) {
        int mrow = wave * 32 + i * 16 + cI;
        #pragma unroll
        for (int kc = 0; kc < 4; ++kc)
            afr[i][kc] = *(const half8*)&xh[mrow * 136 + kc * 32 + quad * 8];
    }
    __syncthreads();

    f32x4 acc[2][8];
    #pragma unroll
    for (int i = 0; i < 2; ++i)
        #pragma unroll
        for (int nt = 0; nt < 8; ++nt) acc[i][nt] = (f32x4){0.f, 0.f, 0.f, 0.f};

    #pragma unroll
    for (int nt = 0; nt < 8; ++nt) {
        const _Float16* wb = WT + (size_t)(nt * 16 + cI) * HDIM + quad * 8;
        half8 bfr[4];
        #pragma unroll
        for (int kc = 0; kc < 4; ++kc) bfr[kc] = *(const half8*)(wb + kc * 32);
        #pragma unroll
        for (int i = 0; i < 2; ++i)
            #pragma unroll
            for (int kc = 0; kc < 4; ++kc)
                acc[i][nt] = __builtin_amdgcn_mfma_f32_16x16x32_f16(afr[i][kc], bfr[kc], acc[i][nt], 0, 0, 0);
    }

    _Float16 (*cs)[136] = (_Float16(*)[136])xh;
    #pragma unroll
    for (int i = 0; i < 2; ++i)
        #pragma unroll
        for (int nt = 0; nt < 8; ++nt)
            #pragma unroll
            for (int r = 0; r < 4; ++r)
                cs[wave * 32 + i * 16 + quad * 4 + r][nt * 16 + cI] = (_Float16)acc[i][nt][r];
    __syncthreads();

    for (int t = tid; t < 128 * 16; t += 256) {
        int r = t >> 4, c8 = t & 15;
        int gr = row0 + r;
        if (gr < n)
            *(float4*)(out + sl_off(gr, c8, n)) = *(float4*)&cs[r][c8 * 8];
    }
}

// R14 XCD-sliced gather, built for deg~16: 4 lanes/node (slot 0..1 x chunk
// 0..1). Each lane serially walks its slot's edges (stride 4, unroll 2),
// loads col directly (no shfl chain), 32-bit slice-relative addressing,
// fdot2 accumulate, one shfl_xor reduction round. slice = blockIdx&7 keeps
// the 3.2 MB slice pinned in one XCD's L2 under round-robin dispatch.
__global__ __launch_bounds__(256) void agg_slice_kernel(
        const _Float16* __restrict__ t, const int* __restrict__ row_ptr,
        const int* __restrict__ col, const float* __restrict__ in_norm,
        const float* __restrict__ bias, _Float16* __restrict__ h, int n) {
    const int s = blockIdx.x & 7;           // slice == XCD under round-robin
    const int g = blockIdx.x >> 3;
    const int tid = threadIdx.x;
    const int rnode = g * 64 + (tid >> 2);
    const bool live = rnode < n;
    const int node = live ? rnode : (n - 1);
    const int slot = (tid >> 1) & 1;
    const int chunk = tid & 1;

    const _Float16* __restrict__ ts = t + (size_t)s * (size_t)n * 16;
    const int beg = row_ptr[node], end = row_ptr[node + 1];
    const int cofs = chunk * 8;

    float f[8] = {};
    for (int e = beg + slot; e < end; e += 4) {
        const int i1 = e + 2;
        const int c0 = col[e];
        half8 v0 = *(const half8*)(ts + c0 * 16 + cofs);
        half8 v1 = {};
        if (i1 < end) {
            const int c1 = col[i1];
            v1 = *(const half8*)(ts + c1 * 16 + cofs);
        }
        accum8(f, v0);
        accum8(f, v1);
    }

    // combine the two slots (tid bit 1)
    #pragma unroll
    for (int q = 0; q < 8; ++q) f[q] += __shfl_xor(f[q], 2, 64);

    if (slot == 0 && live) {
        const float inn = in_norm[node];
        const float* bb = bias + s * 16 + cofs;
        float4 b0 = *(const float4*)bb;
        float4 b1 = *(const float4*)(bb + 4);
        half8 hv;
        hv[0] = (_Float16)fmaxf(f[0] * inn + b0.x, 0.f);
        hv[1] = (_Float16)fmaxf(f[1] * inn + b0.y, 0.f);
        hv[2] = (_Float16)fmaxf(f[2] * inn + b0.z, 0.f);
        hv[3] = (_Float16)fmaxf(f[3] * inn + b0.w, 0.f);
        hv[4] = (_Float16)fmaxf(f[4] * inn + b1.x, 0.f);
        hv[5] = (_Float16)fmaxf(f[5] * inn + b1.y, 0.f);
        hv[6] = (_Float16)fmaxf(f[6] * inn + b1.z, 0.f);
        hv[7] = (_Float16)fmaxf(f[7] * inn + b1.w, 0.f);
        *(half8*)(h + (size_t)s * (size_t)n * 16 + (size_t)node * 16 + cofs) = hv;
    }
}

__global__ void seg_kernel(const float* __restrict__ colsum, const float* __restrict__ Wp,
                           const float* __restrict__ bp, float* __restrict__ segout, float inv_n) {
    int c = threadIdx.x;
    if (c < NCLS) {
        float s = 0.f;
        #pragma unroll 4
        for (int k = 0; k < HDIM; ++k) s = fmaf(colsum[k], Wp[c * HDIM + k], s);
        segout[c] = s * inv_n + bp[c];
    }
}

// CAM via MFMA: CAM[c,n] = dot(Wp[c,:], h3[n,:]). h3 is sliced [8][n][16].
// Block = 128 nodes staged in LDS; per class-tile A load.
__global__ __launch_bounds__(256) void cam_mfma_kernel(
        const _Float16* __restrict__ h, const _Float16* __restrict__ Wph,
        const _Float16* __restrict__ Wpr, float* __restrict__ out,
        float* __restrict__ colsum, int n) {
    __shared__ _Float16 hs[128 * CSTRIDE];      // 35 KB
    const int tid = threadIdx.x;
    const int wave = tid >> 6, lane = tid & 63;
    const int quad = lane >> 4, cI = lane & 15;
    const int n0 = blockIdx.x * 128;

    for (int t = tid; t < 128 * 16; t += 256) {
        int r = t >> 4, c8 = t & 15;
        int gr = n0 + r;
        half8 v = {};
        if (gr < n) v = *(const half8*)(h + sl_off(gr, c8, n));
        *(half8*)&hs[r * CSTRIDE + c8 * 8] = v;
    }
    __syncthreads();

    #pragma unroll
    for (int ct = 0; ct < 3; ++ct) {
        const int cls = ct * 16 + cI;
        const bool av = cls < NCLS;
        const int clc = av ? cls : 0;
        half8 ah[4], ar[4];
        #pragma unroll
        for (int kc = 0; kc < 4; ++kc) {
            half8 z = {};
            half8 vh = *(const half8*)(Wph + clc * HDIM + kc * 32 + quad * 8);
            half8 vr = *(const half8*)(Wpr + clc * HDIM + kc * 32 + quad * 8);
            ah[kc] = av ? vh : z;
            ar[kc] = av ? vr : z;
        }
        #pragma unroll
        for (int t = 0; t < 2; ++t) {
            const int ln = wave * 32 + t * 16 + cI;
            f32x4 acc = (f32x4){0.f, 0.f, 0.f, 0.f};
            #pragma unroll
            for (int kc = 0; kc < 4; ++kc) {
                half8 b = *(const half8*)&hs[ln * CSTRIDE + kc * 32 + quad * 8];
                acc = __builtin_amdgcn_mfma_f32_16x16x32_f16(ah[kc], b, acc, 0, 0, 0);
                acc = __builtin_amdgcn_mfma_f32_16x16x32_f16(ar[kc], b, acc, 0, 0, 0);
            }
            const int node = n0 + ln;
            #pragma unroll
            for (int r = 0; r < 4; ++r) {
                int c2 = ct * 16 + quad * 4 + r;
                if (c2 < NCLS && node < n)
                    out[(size_t)c2 * n + node] = acc[r];
            }
        }
    }

    if (tid < HDIM) {
        float s = 0.f;
        for (int r = 0; r < 128; ++r) s += (float)hs[r * CSTRIDE + tid];
        atomicAdd(&colsum[tid], s);
    }
}

// ---------------- launch ----------------

extern "C" void kernel_launch(void* const* d_in, const int* in_sizes, int n_in,
                              void* d_out, int out_size, void* d_ws, size_t ws_size,
                              hipStream_t stream) {
    const float* features = (const float*)d_in[0];
    const float* W1 = (const float*)d_in[1];
    const float* b1 = (const float*)d_in[2];
    const float* W2 = (const float*)d_in[3];
    const float* b2 = (const float*)d_in[4];
    const float* W3 = (const float*)d_in[5];
    const float* b3 = (const float*)d_in[6];
    const float* Wp = (const float*)d_in[7];
    const float* bp = (const float*)d_in[8];
    const int*   src = (const int*)d_in[9];
    const int*   dst = (const int*)d_in[10];

    const int N = in_sizes[0] / HDIM;
    const int E = in_sizes[9];
    const int K = (N + BSZ - 1) >> BSH;           // buckets (<= KMAX)
    const int NB = (E + EPB - 1) / EPB;           // <= NBMAX
    float* out = (float*)d_out;

    // workspace carve-up
    char* ws = (char*)d_ws;
    size_t off = 0;
    int* bcnt   = (int*)(ws + off); off += KMAX * 4;
    int* sbcnt  = (int*)(ws + off); off += KMAX * 4;
    float* colsum = (float*)(ws + off); off += 128 * 4;
    int* bbase  = (int*)(ws + off); off += (KMAX + 1) * 4;
    int* sbase  = (int*)(ws + off); off += (KMAX + 1) * 4;
    int* cntD   = (int*)(ws + off); off += (size_t)KMAX * NBMAX * 4;   // -> baseD
    int* cntS   = (int*)(ws + off); off += (size_t)KMAX * NBMAX * 4;   // -> baseS
    int* row_ptr = (int*)(ws + off); off += ((size_t)N + 1) * 4; off = (off + 15) & ~(size_t)15;
    int* col_idx = (int*)(ws + off); off += (size_t)E * 4; off = (off + 15) & ~(size_t)15;
    float* out_norm = (float*)(ws + off); off += (size_t)N * 4;
    float* in_norm  = (float*)(ws + off); off += (size_t)N * 4; off = (off + 255) & ~(size_t)255;
    _Float16* WT  = (_Float16*)(ws + off); off += 3 * HDIM * HDIM * 2;
    _Float16* Wph = (_Float16*)(ws + off); off += NCLS * HDIM * 2;
    _Float16* Wpr = (_Float16*)(ws + off); off += NCLS * HDIM * 2; off = (off + 255) & ~(size_t)255;
    _Float16* Bh  = (_Float16*)(ws + off); off += (size_t)N * HDIM * 2; off = (off + 255) & ~(size_t)255;
    _Float16* F0h = (_Float16*)(ws + off); off += (size_t)N * HDIM * 2; off = (off + 255) & ~(size_t)255;
    (void)ws_size; (void)n_in; (void)out_size;

    // aliases: rank in Bh (first written by gemm1); dbuf/sbuf in F0h (first
    // written by agg1, after finish_kernel consumed them)
    unsigned* rank = (unsigned*)Bh;                   // E*4 B
    unsigned* dbuf = (unsigned*)F0h;                  // E*4 B (packed src|local<<24)
    int*      sbuf = (int*)((char*)F0h + (size_t)E * 4);  // E*4 B

    const int nzero = 2 * KMAX + 128;
    zero_kernel<<<(nzero + 255) / 256, 256, 0, stream>>>((int*)ws, nzero);
    count_rank_kernel<<<NB, 256, 0, stream>>>(src, dst, bcnt, sbcnt, rank, cntD, cntS, K, E);
    bucket_scan_kernel<<<1, 64, 0, stream>>>(bcnt, sbcnt, bbase, sbase, K);
    basebk_kernel<<<2 * K, 64, 0, stream>>>(bbase, sbase, cntD, cntS, K, NB);
    scatter_kernel<<<NB, 256, 0, stream>>>(src, dst, rank, cntD, cntS, dbuf, sbuf, K, E);

    const int conv_blocks = (3 * HDIM * HDIM + NCLS * HDIM + 255) / 256;
    finish_kernel<<<2 * K + conv_blocks, 256, 0, stream>>>(
        dbuf, sbuf, bbase, sbase, row_ptr, in_norm, out_norm, col_idx,
        W1, W2, W3, Wp, WT, Wph, Wpr, N, K, E);

    const int gemm_blocks = (N + 127) / 128;
    const int agg_blocks  = ((N + 63) / 64) * 8;     // node-groups x 8 slices

    // layer 1
    gemm_mfma_kernel<float><<<gemm_blocks, 256, 0, stream>>>(features, WT, out_norm, Bh, N);
    agg_slice_kernel<<<agg_blocks, 256, 0, stream>>>(Bh, row_ptr, col_idx, in_norm, b1, F0h, N);
    // layer 2
    gemm_mfma_kernel<_Float16><<<gemm_blocks, 256, 0, stream>>>(F0h, WT + HDIM * HDIM, out_norm, Bh, N);
    agg_slice_kernel<<<agg_blocks, 256, 0, stream>>>(Bh, row_ptr, col_idx, in_norm, b2, F0h, N);
    // layer 3 (h3 sliced fp16 -> F0h)
    gemm_mfma_kernel<_Float16><<<gemm_blocks, 256, 0, stream>>>(F0h, WT + 2 * HDIM * HDIM, out_norm, Bh, N);
    agg_slice_kernel<<<agg_blocks, 256, 0, stream>>>(Bh, row_ptr, col_idx, in_norm, b3, F0h, N);

    // head: cam (MFMA, fused colsum) then seg
    cam_mfma_kernel<<<(N + 127) / 128, 256, 0, stream>>>(F0h, Wph, Wpr, out + NCLS, colsum, N);
    seg_kernel<<<1, 64, 0, stream>>>(colsum, Wp, bp, out, 1.0f / (float)N);
}

// Round 4
// 515.021 us; speedup vs baseline: 1.0578x; 1.0566x over previous
//
#include <hip/hip_runtime.h>
#include <hip/hip_bf16.h>
#include <hip/hip_fp16.h>

// GCN: 3 layers of  h = relu(in_norm * A_pull( (out_norm*x) @ W ) + b)
// then seg_output = (mean_n h3) @ Wp^T + bp  and  CAM = Wp @ h3^T.
// Preprocessing (R12): one count+rank pass, base-table scans, pure-streaming
// scatter, fused csr+outdeg+convw. No scattered global atomics.
// R13: XCD-sliced fp16 tensors [8][N][16] (3.2 MB/slice < 4 MB per-XCD L2);
// agg grid = groups x 8, slice = blockIdx&7 -> round-robin dispatch pins each
// slice into one XCD's L2. FETCH 179.5 -> 44 MB (now 74 MB incl 8x col
// re-read — cheap at L3 BW, not the limiter).
// R14/R15: 4 lanes/node (2 slots x 2 chunks), direct col loads, fdot2
// accumulate, 1 shfl_xor round. Result: VALUBusy 71->24%, but dur only
// 92->88 us: pure dependent-load latency (col -> row serial chain, 2 rows
// in flight/lane).
// R16: 2-stage software pipeline, unroll 4: prefetch next window's 4 col
// indices while current window's 4 row loads are in flight. Per-window
// latency max(Lcol,Lrow) instead of Lcol+Lrow; 4 rows in flight per lane.

#define HDIM 128
#define NCLS 40
#define BSH 8
#define BSZ 256          // nodes per bucket
#define KMAX 512
#define NBMAX 512
#define EPB 4096         // edges per count/scatter block
#define CSTRIDE 140      // cam LDS row stride (fp16)

typedef _Float16 half8 __attribute__((ext_vector_type(8)));
typedef _Float16 half2t __attribute__((ext_vector_type(2)));
typedef float f32x4 __attribute__((ext_vector_type(4)));

// sliced layout helper: feature chunk c8 (8 fp16) of node gr in [8][n][16]
__device__ __forceinline__ size_t sl_off(int gr, int c8, int n) {
    return ((size_t)(c8 >> 1)) * (size_t)n * 16 + (size_t)gr * 16 + (size_t)(c8 & 1) * 8;
}

// accumulate 8 fp16 into 8 f32 sums; fdot2 = 1 VALU per element, exact
__device__ __forceinline__ void accum8(float* f, half8 v) {
#if __has_builtin(__builtin_amdgcn_fdot2)
    const half2t m0 = {(_Float16)1.0f, (_Float16)0.0f};
    const half2t m1 = {(_Float16)0.0f, (_Float16)1.0f};
    half2t a0 = __builtin_shufflevector(v, v, 0, 1);
    half2t a1 = __builtin_shufflevector(v, v, 2, 3);
    half2t a2 = __builtin_shufflevector(v, v, 4, 5);
    half2t a3 = __builtin_shufflevector(v, v, 6, 7);
    f[0] = __builtin_amdgcn_fdot2(a0, m0, f[0], false);
    f[1] = __builtin_amdgcn_fdot2(a0, m1, f[1], false);
    f[2] = __builtin_amdgcn_fdot2(a1, m0, f[2], false);
    f[3] = __builtin_amdgcn_fdot2(a1, m1, f[3], false);
    f[4] = __builtin_amdgcn_fdot2(a2, m0, f[4], false);
    f[5] = __builtin_amdgcn_fdot2(a2, m1, f[5], false);
    f[6] = __builtin_amdgcn_fdot2(a3, m0, f[6], false);
    f[7] = __builtin_amdgcn_fdot2(a3, m1, f[7], false);
#else
    #pragma unroll
    for (int q = 0; q < 8; ++q) f[q] += (float)v[q];
#endif
}

// ---------------- graph preprocessing ----------------

__global__ void zero_kernel(int* __restrict__ p, int n) {
    int i = blockIdx.x * blockDim.x + threadIdx.x;
    if (i < n) p[i] = 0;
}

// One pass: LDS bucket histograms (dst+src), per-edge packed ranks,
// per-(bucket,block) count tables (k-major), global bucket totals.
__global__ __launch_bounds__(256) void count_rank_kernel(
        const int* __restrict__ src, const int* __restrict__ dst,
        int* __restrict__ bcnt, int* __restrict__ sbcnt,
        unsigned* __restrict__ rank, int* __restrict__ cntD, int* __restrict__ cntS,
        int K, int E) {
    __shared__ int lc[KMAX], ls[KMAX];
    const int tid = threadIdx.x;
    lc[tid] = 0; lc[tid + 256] = 0; ls[tid] = 0; ls[tid + 256] = 0;
    __syncthreads();
    const int base = blockIdx.x * EPB;
    const int lim = min(EPB, E - base);
    for (int i = tid; i < lim; i += 256) {
        int kd = dst[base + i] >> BSH, ks = src[base + i] >> BSH;
        unsigned rd = (unsigned)atomicAdd(&lc[kd], 1);
        unsigned rs = (unsigned)atomicAdd(&ls[ks], 1);
        rank[base + i] = rd | (rs << 16);
    }
    __syncthreads();
    for (int t = tid; t < K; t += 256) {
        cntD[t * NBMAX + blockIdx.x] = lc[t];
        cntS[t * NBMAX + blockIdx.x] = ls[t];
        if (lc[t]) atomicAdd(&bcnt[t], lc[t]);
        if (ls[t]) atomicAdd(&sbcnt[t], ls[t]);
    }
}

// one wave: exclusive scan of both bucket-total arrays (K <= KMAX)
__global__ void bucket_scan_kernel(const int* __restrict__ a, const int* __restrict__ b,
                                   int* __restrict__ abase, int* __restrict__ bbase, int K) {
    const int lane = threadIdx.x;   // blockDim = 64
    int ca = 0, cb = 0;
    for (int base = 0; base < K; base += 64) {
        int va = (base + lane < K) ? a[base + lane] : 0;
        int vb = (base + lane < K) ? b[base + lane] : 0;
        int ia = va, ib = vb;
        #pragma unroll
        for (int d = 1; d < 64; d <<= 1) {
            int oa = __shfl_up(ia, d, 64);
            int ob = __shfl_up(ib, d, 64);
            if (lane >= d) { ia += oa; ib += ob; }
        }
        if (base + lane < K) { abase[base + lane] = ca + ia - va; bbase[base + lane] = cb + ib - vb; }
        ca += __shfl(ia, 63, 64);
        cb += __shfl(ib, 63, 64);
    }
    if (lane == 0) { abase[K] = ca; bbase[K] = cb; }
}

// grid 2K x 64: convert count tables (k-major) to absolute base tables in place
__global__ void basebk_kernel(const int* __restrict__ bbase, const int* __restrict__ sbase,
                              int* __restrict__ cntD, int* __restrict__ cntS,
                              int K, int NB) {
    const bool isS = (int)blockIdx.x >= K;
    const int k = isS ? (blockIdx.x - K) : blockIdx.x;
    int* tbl = isS ? cntS : cntD;
    int run = isS ? sbase[k] : bbase[k];
    const int lane = threadIdx.x;   // 64
    for (int b0 = 0; b0 < NB; b0 += 64) {
        int v = (b0 + lane < NB) ? tbl[k * NBMAX + b0 + lane] : 0;
        int incl = v;
        #pragma unroll
        for (int d = 1; d < 64; d <<= 1) {
            int o = __shfl_up(incl, d, 64);
            if (lane >= d) incl += o;
        }
        if (b0 + lane < NB) tbl[k * NBMAX + b0 + lane] = run + incl - v;
        run += __shfl(incl, 63, 64);
    }
}

// pure streaming scatter: no LDS counting, no atomics
__global__ __launch_bounds__(256) void scatter_kernel(
        const int* __restrict__ src, const int* __restrict__ dst,
        const unsigned* __restrict__ rank,
        const int* __restrict__ baseD, const int* __restrict__ baseS,
        unsigned* __restrict__ dbuf, int* __restrict__ sbuf, int K, int E) {
    __shared__ int ldsD[KMAX], ldsS[KMAX];
    const int tid = threadIdx.x, b = blockIdx.x;
    for (int t = tid; t < K; t += 256) {
        ldsD[t] = baseD[t * NBMAX + b];
        ldsS[t] = baseS[t * NBMAX + b];
    }
    __syncthreads();
    const int base = b * EPB;
    const int lim = min(EPB, E - base);
    for (int i = tid; i < lim; i += 256) {
        int d = dst[base + i], s = src[base + i];
        unsigned r = rank[base + i];
        dbuf[ldsD[d >> BSH] + (r & 0xFFFFu)] = (unsigned)s | ((unsigned)(d & (BSZ - 1)) << 24);
        sbuf[ldsS[s >> BSH] + (r >> 16)] = s;
    }
}

// fused: blocks [0,K) build CSR; [K,2K) out_norm; [2K,..) weight conversion
__global__ __launch_bounds__(256) void finish_kernel(
        const unsigned* __restrict__ dbuf, const int* __restrict__ sbuf,
        const int* __restrict__ bbase, const int* __restrict__ sbase,
        int* __restrict__ row_ptr, float* __restrict__ in_norm,
        float* __restrict__ out_norm, int* __restrict__ col,
        const float* __restrict__ W1, const float* __restrict__ W2,
        const float* __restrict__ W3, const float* __restrict__ Wp,
        _Float16* __restrict__ WT, _Float16* __restrict__ Wph, _Float16* __restrict__ Wpr,
        int N, int K, int E) {
    __shared__ int cnt[BSZ], lsc[BSZ];
    __shared__ int wsum[4];
    const int blk = blockIdx.x, tid = threadIdx.x;

    if (blk < K) {
        // ---- build CSR for dst-bucket blk ----
        const int k = blk;
        const int node0 = k << BSH;
        const int beg = bbase[k], end = bbase[k + 1];
        cnt[tid] = 0;
        __syncthreads();
        for (int i = beg + tid; i < end; i += 256)
            atomicAdd(&cnt[dbuf[i] >> 24], 1);
        __syncthreads();
        const int c0 = cnt[tid];
        int incl = c0;
        const int lane = tid & 63, w = tid >> 6;
        #pragma unroll
        for (int d = 1; d < 64; d <<= 1) {
            int o = __shfl_up(incl, d, 64);
            if (lane >= d) incl += o;
        }
        if (lane == 63) wsum[w] = incl;
        __syncthreads();
        int off = 0;
        for (int j = 0; j < w; ++j) off += wsum[j];
        const int excl = off + incl - c0;
        lsc[tid] = excl;
        const int node = node0 + tid;
        if (node < N) { row_ptr[node] = beg + excl; in_norm[node] = 1.0f / sqrtf((float)max(c0, 1)); }
        if (k == K - 1 && tid == 0) row_ptr[N] = E;
        __syncthreads();
        cnt[tid] = 0;
        __syncthreads();
        for (int i = beg + tid; i < end; i += 256) {
            unsigned e = dbuf[i];
            int local = e >> 24;
            int r = atomicAdd(&cnt[local], 1);
            col[beg + lsc[local] + r] = (int)(e & 0xFFFFFFu);
        }
    } else if (blk < 2 * K) {
        // ---- out_norm for src-bucket blk-K ----
        const int k = blk - K;
        const int beg = sbase[k], end = sbase[k + 1];
        cnt[tid] = 0;
        __syncthreads();
        for (int i = beg + tid; i < end; i += 256)
            atomicAdd(&cnt[sbuf[i] & (BSZ - 1)], 1);
        __syncthreads();
        const int n0 = (k << BSH) + tid;
        if (n0 < N) out_norm[n0] = 1.0f / sqrtf((float)max(cnt[tid], 1));
    } else {
        // ---- weight conversion ----
        int i = (blk - 2 * K) * 256 + tid;
        if (i < 3 * HDIM * HDIM) {
            int w = i >> 14, r = i & (HDIM * HDIM - 1);
            int nn = r >> 7, kk = r & 127;
            const float* W = (w == 0) ? W1 : (w == 1) ? W2 : W3;
            WT[i] = (_Float16)W[kk * HDIM + nn];
        } else if (i < 3 * HDIM * HDIM + NCLS * HDIM) {
            int j = i - 3 * HDIM * HDIM;
            float v = Wp[j];
            _Float16 hi = (_Float16)v;
            Wph[j] = hi;
            Wpr[j] = (_Float16)(v - (float)hi);
        }
    }
}

// ---------------- dense compute ----------------

// out[m,:] = fp16( (out_norm[m]*x[m,:]) @ W ) via mfma_f32_16x16x32_f16.
// 128-row block, 2 m-tiles/wave; fp16 LDS staging; IT = float (row-major
// input) or _Float16 (sliced input). Output always sliced [8][n][16].
template <typename IT>
__global__ __launch_bounds__(256) void gemm_mfma_kernel(
        const IT* __restrict__ x, const _Float16* __restrict__ WT,
        const float* __restrict__ out_norm, _Float16* __restrict__ out, int n) {
    __shared__ _Float16 xh[128 * 136];          // 34.8 KB; also epilogue cs
    const int tid = threadIdx.x;
    const int wave = tid >> 6, lane = tid & 63;
    const int quad = lane >> 4, cI = lane & 15;
    const int row0 = blockIdx.x * 128;

    for (int t = tid; t < 128 * 16; t += 256) {
        int r = t >> 4, c8 = t & 15;
        int gr = row0 + r;
        half8 hv = {};
        if (gr < n) {
            float sc = out_norm[gr];
            if constexpr (sizeof(IT) == 2) {
                half8 v = *(const half8*)((const _Float16*)x + sl_off(gr, c8, n));
                #pragma unroll
                for (int q = 0; q < 8; ++q) hv[q] = (_Float16)((float)v[q] * sc);
            } else {
                const float* xr = (const float*)x + (size_t)gr * HDIM + c8 * 8;
                float4 u = *(const float4*)xr;
                float4 v = *(const float4*)(xr + 4);
                hv[0] = (_Float16)(u.x * sc); hv[1] = (_Float16)(u.y * sc);
                hv[2] = (_Float16)(u.z * sc); hv[3] = (_Float16)(u.w * sc);
                hv[4] = (_Float16)(v.x * sc); hv[5] = (_Float16)(v.y * sc);
                hv[6] = (_Float16)(v.z * sc); hv[7] = (_Float16)(v.w * sc);
            }
        }
        *(half8*)&xh[r * 136 + c8 * 8] = hv;
    }
    __syncthreads();

    half8 afr[2][4];
    #pragma unroll
    for (int i = 0; i < 2; ++i) {
        int mrow = wave * 32 + i * 16 + cI;
        #pragma unroll
        for (int kc = 0; kc < 4; ++kc)
            afr[i][kc] = *(const half8*)&xh[mrow * 136 + kc * 32 + quad * 8];
    }
    __syncthreads();

    f32x4 acc[2][8];
    #pragma unroll
    for (int i = 0; i < 2; ++i)
        #pragma unroll
        for (int nt = 0; nt < 8; ++nt) acc[i][nt] = (f32x4){0.f, 0.f, 0.f, 0.f};

    #pragma unroll
    for (int nt = 0; nt < 8; ++nt) {
        const _Float16* wb = WT + (size_t)(nt * 16 + cI) * HDIM + quad * 8;
        half8 bfr[4];
        #pragma unroll
        for (int kc = 0; kc < 4; ++kc) bfr[kc] = *(const half8*)(wb + kc * 32);
        #pragma unroll
        for (int i = 0; i < 2; ++i)
            #pragma unroll
            for (int kc = 0; kc < 4; ++kc)
                acc[i][nt] = __builtin_amdgcn_mfma_f32_16x16x32_f16(afr[i][kc], bfr[kc], acc[i][nt], 0, 0, 0);
    }

    _Float16 (*cs)[136] = (_Float16(*)[136])xh;
    #pragma unroll
    for (int i = 0; i < 2; ++i)
        #pragma unroll
        for (int nt = 0; nt < 8; ++nt)
            #pragma unroll
            for (int r = 0; r < 4; ++r)
                cs[wave * 32 + i * 16 + quad * 4 + r][nt * 16 + cI] = (_Float16)acc[i][nt][r];
    __syncthreads();

    for (int t = tid; t < 128 * 16; t += 256) {
        int r = t >> 4, c8 = t & 15;
        int gr = row0 + r;
        if (gr < n)
            *(float4*)(out + sl_off(gr, c8, n)) = *(float4*)&cs[r][c8 * 8];
    }
}

// R16 XCD-sliced gather: 4 lanes/node (slot 0..1 x chunk 0..1). Per lane a
// 2-stage software pipeline over windows of 4 edges (stride 2 within slot):
// next window's col indices load while current window's 4 row loads are in
// flight -> per-window latency ~max(Lcol,Lrow), 4 rows in flight per lane.
// fdot2 accumulate, single shfl_xor reduction round. slice = blockIdx&7
// keeps the 3.2 MB slice pinned in one XCD's L2 under round-robin dispatch.
__global__ __launch_bounds__(256) void agg_slice_kernel(
        const _Float16* __restrict__ t, const int* __restrict__ row_ptr,
        const int* __restrict__ col, const float* __restrict__ in_norm,
        const float* __restrict__ bias, _Float16* __restrict__ h, int n) {
    const int s = blockIdx.x & 7;           // slice == XCD under round-robin
    const int g = blockIdx.x >> 3;
    const int tid = threadIdx.x;
    const int rnode = g * 64 + (tid >> 2);
    const bool live = rnode < n;
    const int node = live ? rnode : (n - 1);
    const int slot = (tid >> 1) & 1;
    const int chunk = tid & 1;

    const _Float16* __restrict__ ts = t + (size_t)s * (size_t)n * 16;
    const int beg = row_ptr[node], end = row_ptr[node + 1];
    const int cofs = chunk * 8;

    float f[8] = {};
    int e = beg + slot;
    int c0 = 0, c1 = 0, c2 = 0, c3 = 0;
    bool have = (e + 6 < end);
    if (have) { c0 = col[e]; c1 = col[e + 2]; c2 = col[e + 4]; c3 = col[e + 6]; }
    while (have) {
        const int en = e + 8;
        const bool nhave = (en + 6 < end);
        int n0 = 0, n1 = 0, n2 = 0, n3 = 0;
        if (nhave) { n0 = col[en]; n1 = col[en + 2]; n2 = col[en + 4]; n3 = col[en + 6]; }
        half8 v0 = *(const half8*)(ts + c0 * 16 + cofs);
        half8 v1 = *(const half8*)(ts + c1 * 16 + cofs);
        half8 v2 = *(const half8*)(ts + c2 * 16 + cofs);
        half8 v3 = *(const half8*)(ts + c3 * 16 + cofs);
        accum8(f, v0);
        accum8(f, v1);
        accum8(f, v2);
        accum8(f, v3);
        c0 = n0; c1 = n1; c2 = n2; c3 = n3;
        e = en; have = nhave;
    }
    // tail: fewer than 4 lane-edges remain
    for (; e < end; e += 2) {
        const int c = col[e];
        half8 v = *(const half8*)(ts + c * 16 + cofs);
        accum8(f, v);
    }

    // combine the two slots (tid bit 1)
    #pragma unroll
    for (int q = 0; q < 8; ++q) f[q] += __shfl_xor(f[q], 2, 64);

    if (slot == 0 && live) {
        const float inn = in_norm[node];
        const float* bb = bias + s * 16 + cofs;
        float4 b0 = *(const float4*)bb;
        float4 b1 = *(const float4*)(bb + 4);
        half8 hv;
        hv[0] = (_Float16)fmaxf(f[0] * inn + b0.x, 0.f);
        hv[1] = (_Float16)fmaxf(f[1] * inn + b0.y, 0.f);
        hv[2] = (_Float16)fmaxf(f[2] * inn + b0.z, 0.f);
        hv[3] = (_Float16)fmaxf(f[3] * inn + b0.w, 0.f);
        hv[4] = (_Float16)fmaxf(f[4] * inn + b1.x, 0.f);
        hv[5] = (_Float16)fmaxf(f[5] * inn + b1.y, 0.f);
        hv[6] = (_Float16)fmaxf(f[6] * inn + b1.z, 0.f);
        hv[7] = (_Float16)fmaxf(f[7] * inn + b1.w, 0.f);
        *(half8*)(h + (size_t)s * (size_t)n * 16 + (size_t)node * 16 + cofs) = hv;
    }
}

__global__ void seg_kernel(const float* __restrict__ colsum, const float* __restrict__ Wp,
                           const float* __restrict__ bp, float* __restrict__ segout, float inv_n) {
    int c = threadIdx.x;
    if (c < NCLS) {
        float s = 0.f;
        #pragma unroll 4
        for (int k = 0; k < HDIM; ++k) s = fmaf(colsum[k], Wp[c * HDIM + k], s);
        segout[c] = s * inv_n + bp[c];
    }
}

// CAM via MFMA: CAM[c,n] = dot(Wp[c,:], h3[n,:]). h3 is sliced [8][n][16].
// Block = 128 nodes staged in LDS; per class-tile A load.
__global__ __launch_bounds__(256) void cam_mfma_kernel(
        const _Float16* __restrict__ h, const _Float16* __restrict__ Wph,
        const _Float16* __restrict__ Wpr, float* __restrict__ out,
        float* __restrict__ colsum, int n) {
    __shared__ _Float16 hs[128 * CSTRIDE];      // 35 KB
    const int tid = threadIdx.x;
    const int wave = tid >> 6, lane = tid & 63;
    const int quad = lane >> 4, cI = lane & 15;
    const int n0 = blockIdx.x * 128;

    for (int t = tid; t < 128 * 16; t += 256) {
        int r = t >> 4, c8 = t & 15;
        int gr = n0 + r;
        half8 v = {};
        if (gr < n) v = *(const half8*)(h + sl_off(gr, c8, n));
        *(half8*)&hs[r * CSTRIDE + c8 * 8] = v;
    }
    __syncthreads();

    #pragma unroll
    for (int ct = 0; ct < 3; ++ct) {
        const int cls = ct * 16 + cI;
        const bool av = cls < NCLS;
        const int clc = av ? cls : 0;
        half8 ah[4], ar[4];
        #pragma unroll
        for (int kc = 0; kc < 4; ++kc) {
            half8 z = {};
            half8 vh = *(const half8*)(Wph + clc * HDIM + kc * 32 + quad * 8);
            half8 vr = *(const half8*)(Wpr + clc * HDIM + kc * 32 + quad * 8);
            ah[kc] = av ? vh : z;
            ar[kc] = av ? vr : z;
        }
        #pragma unroll
        for (int t = 0; t < 2; ++t) {
            const int ln = wave * 32 + t * 16 + cI;
            f32x4 acc = (f32x4){0.f, 0.f, 0.f, 0.f};
            #pragma unroll
            for (int kc = 0; kc < 4; ++kc) {
                half8 b = *(const half8*)&hs[ln * CSTRIDE + kc * 32 + quad * 8];
                acc = __builtin_amdgcn_mfma_f32_16x16x32_f16(ah[kc], b, acc, 0, 0, 0);
                acc = __builtin_amdgcn_mfma_f32_16x16x32_f16(ar[kc], b, acc, 0, 0, 0);
            }
            const int node = n0 + ln;
            #pragma unroll
            for (int r = 0; r < 4; ++r) {
                int c2 = ct * 16 + quad * 4 + r;
                if (c2 < NCLS && node < n)
                    out[(size_t)c2 * n + node] = acc[r];
            }
        }
    }

    if (tid < HDIM) {
        float s = 0.f;
        for (int r = 0; r < 128; ++r) s += (float)hs[r * CSTRIDE + tid];
        atomicAdd(&colsum[tid], s);
    }
}

// ---------------- launch ----------------

extern "C" void kernel_launch(void* const* d_in, const int* in_sizes, int n_in,
                              void* d_out, int out_size, void* d_ws, size_t ws_size,
                              hipStream_t stream) {
    const float* features = (const float*)d_in[0];
    const float* W1 = (const float*)d_in[1];
    const float* b1 = (const float*)d_in[2];
    const float* W2 = (const float*)d_in[3];
    const float* b2 = (const float*)d_in[4];
    const float* W3 = (const float*)d_in[5];
    const float* b3 = (const float*)d_in[6];
    const float* Wp = (const float*)d_in[7];
    const float* bp = (const float*)d_in[8];
    const int*   src = (const int*)d_in[9];
    const int*   dst = (const int*)d_in[10];

    const int N = in_sizes[0] / HDIM;
    const int E = in_sizes[9];
    const int K = (N + BSZ - 1) >> BSH;           // buckets (<= KMAX)
    const int NB = (E + EPB - 1) / EPB;           // <= NBMAX
    float* out = (float*)d_out;

    // workspace carve-up
    char* ws = (char*)d_ws;
    size_t off = 0;
    int* bcnt   = (int*)(ws + off); off += KMAX * 4;
    int* sbcnt  = (int*)(ws + off); off += KMAX * 4;
    float* colsum = (float*)(ws + off); off += 128 * 4;
    int* bbase  = (int*)(ws + off); off += (KMAX + 1) * 4;
    int* sbase  = (int*)(ws + off); off += (KMAX + 1) * 4;
    int* cntD   = (int*)(ws + off); off += (size_t)KMAX * NBMAX * 4;   // -> baseD
    int* cntS   = (int*)(ws + off); off += (size_t)KMAX * NBMAX * 4;   // -> baseS
    int* row_ptr = (int*)(ws + off); off += ((size_t)N + 1) * 4; off = (off + 15) & ~(size_t)15;
    int* col_idx = (int*)(ws + off); off += (size_t)E * 4; off = (off + 15) & ~(size_t)15;
    float* out_norm = (float*)(ws + off); off += (size_t)N * 4;
    float* in_norm  = (float*)(ws + off); off += (size_t)N * 4; off = (off + 255) & ~(size_t)255;
    _Float16* WT  = (_Float16*)(ws + off); off += 3 * HDIM * HDIM * 2;
    _Float16* Wph = (_Float16*)(ws + off); off += NCLS * HDIM * 2;
    _Float16* Wpr = (_Float16*)(ws + off); off += NCLS * HDIM * 2; off = (off + 255) & ~(size_t)255;
    _Float16* Bh  = (_Float16*)(ws + off); off += (size_t)N * HDIM * 2; off = (off + 255) & ~(size_t)255;
    _Float16* F0h = (_Float16*)(ws + off); off += (size_t)N * HDIM * 2; off = (off + 255) & ~(size_t)255;
    (void)ws_size; (void)n_in; (void)out_size;

    // aliases: rank in Bh (first written by gemm1); dbuf/sbuf in F0h (first
    // written by agg1, after finish_kernel consumed them)
    unsigned* rank = (unsigned*)Bh;                   // E*4 B
    unsigned* dbuf = (unsigned*)F0h;                  // E*4 B (packed src|local<<24)
    int*      sbuf = (int*)((char*)F0h + (size_t)E * 4);  // E*4 B

    const int nzero = 2 * KMAX + 128;
    zero_kernel<<<(nzero + 255) / 256, 256, 0, stream>>>((int*)ws, nzero);
    count_rank_kernel<<<NB, 256, 0, stream>>>(src, dst, bcnt, sbcnt, rank, cntD, cntS, K, E);
    bucket_scan_kernel<<<1, 64, 0, stream>>>(bcnt, sbcnt, bbase, sbase, K);
    basebk_kernel<<<2 * K, 64, 0, stream>>>(bbase, sbase, cntD, cntS, K, NB);
    scatter_kernel<<<NB, 256, 0, stream>>>(src, dst, rank, cntD, cntS, dbuf, sbuf, K, E);

    const int conv_blocks = (3 * HDIM * HDIM + NCLS * HDIM + 255) / 256;
    finish_kernel<<<2 * K + conv_blocks, 256, 0, stream>>>(
        dbuf, sbuf, bbase, sbase, row_ptr, in_norm, out_norm, col_idx,
        W1, W2, W3, Wp, WT, Wph, Wpr, N, K, E);

    const int gemm_blocks = (N + 127) / 128;
    const int agg_blocks  = ((N + 63) / 64) * 8;     // node-groups x 8 slices

    // layer 1
    gemm_mfma_kernel<float><<<gemm_blocks, 256, 0, stream>>>(features, WT, out_norm, Bh, N);
    agg_slice_kernel<<<agg_blocks, 256, 0, stream>>>(Bh, row_ptr, col_idx, in_norm, b1, F0h, N);
    // layer 2
    gemm_mfma_kernel<_Float16><<<gemm_blocks, 256, 0, stream>>>(F0h, WT + HDIM * HDIM, out_norm, Bh, N);
    agg_slice_kernel<<<agg_blocks, 256, 0, stream>>>(Bh, row_ptr, col_idx, in_norm, b2, F0h, N);
    // layer 3 (h3 sliced fp16 -> F0h)
    gemm_mfma_kernel<_Float16><<<gemm_blocks, 256, 0, stream>>>(F0h, WT + 2 * HDIM * HDIM, out_norm, Bh, N);
    agg_slice_kernel<<<agg_blocks, 256, 0, stream>>>(Bh, row_ptr, col_idx, in_norm, b3, F0h, N);

    // head: cam (MFMA, fused colsum) then seg
    cam_mfma_kernel<<<(N + 127) / 128, 256, 0, stream>>>(F0h, Wph, Wpr, out + NCLS, colsum, N);
    seg_kernel<<<1, 64, 0, stream>>>(colsum, Wp, bp, out, 1.0f / (float)N);
}

// Round 5
// 505.385 us; speedup vs baseline: 1.0780x; 1.0191x over previous
//
#include <hip/hip_runtime.h>
#include <hip/hip_bf16.h>
#include <hip/hip_fp16.h>

// GCN: 3 layers of  h = relu(in_norm * A_pull( (out_norm*x) @ W ) + b)
// then seg_output = (mean_n h3) @ Wp^T + bp  and  CAM = Wp @ h3^T.
// Preprocessing (R12): one count+rank pass, base-table scans, pure-streaming
// scatter, fused csr+outdeg+convw. No scattered global atomics.
// R13: XCD-sliced fp16 tensors [8][N][16] (3.2 MB/slice < 4 MB per-XCD L2);
// agg grid = groups x 8, slice = blockIdx&7 -> round-robin dispatch pins each
// slice into one XCD's L2. FETCH 179.5 -> 44 MB.
// R14-R16: gather shape iterations. MLP ladder: ~4 rows in flight 92us ->
// 2/lane 88us -> 4/lane+col prefetch 77us. Still latency-bound (VALUBusy 29%,
// HBM 17%).
// R17: max-MLP shape. 2 lanes/node (chunk 0/1): no shfl reduction, lane owns
// its 8 output features and the node's whole contiguous col list. 8-deep
// row window, software pipelined with next window's 8 col loads -> ~16
// outstanding requests per lane. Unguarded full windows; single guarded tail
// (dummy loads hit row 0, value-zeroed). Discriminates concurrency-limit vs
// L2 scattered-request ceiling.

#define HDIM 128
#define NCLS 40
#define BSH 8
#define BSZ 256          // nodes per bucket
#define KMAX 512
#define NBMAX 512
#define EPB 4096         // edges per count/scatter block
#define CSTRIDE 140      // cam LDS row stride (fp16)

typedef _Float16 half8 __attribute__((ext_vector_type(8)));
typedef _Float16 half2t __attribute__((ext_vector_type(2)));
typedef float f32x4 __attribute__((ext_vector_type(4)));

// sliced layout helper: feature chunk c8 (8 fp16) of node gr in [8][n][16]
__device__ __forceinline__ size_t sl_off(int gr, int c8, int n) {
    return ((size_t)(c8 >> 1)) * (size_t)n * 16 + (size_t)gr * 16 + (size_t)(c8 & 1) * 8;
}

// accumulate 8 fp16 into 8 f32 sums; fdot2 = 1 VALU per element, exact
__device__ __forceinline__ void accum8(float* f, half8 v) {
#if __has_builtin(__builtin_amdgcn_fdot2)
    const half2t m0 = {(_Float16)1.0f, (_Float16)0.0f};
    const half2t m1 = {(_Float16)0.0f, (_Float16)1.0f};
    half2t a0 = __builtin_shufflevector(v, v, 0, 1);
    half2t a1 = __builtin_shufflevector(v, v, 2, 3);
    half2t a2 = __builtin_shufflevector(v, v, 4, 5);
    half2t a3 = __builtin_shufflevector(v, v, 6, 7);
    f[0] = __builtin_amdgcn_fdot2(a0, m0, f[0], false);
    f[1] = __builtin_amdgcn_fdot2(a0, m1, f[1], false);
    f[2] = __builtin_amdgcn_fdot2(a1, m0, f[2], false);
    f[3] = __builtin_amdgcn_fdot2(a1, m1, f[3], false);
    f[4] = __builtin_amdgcn_fdot2(a2, m0, f[4], false);
    f[5] = __builtin_amdgcn_fdot2(a2, m1, f[5], false);
    f[6] = __builtin_amdgcn_fdot2(a3, m0, f[6], false);
    f[7] = __builtin_amdgcn_fdot2(a3, m1, f[7], false);
#else
    #pragma unroll
    for (int q = 0; q < 8; ++q) f[q] += (float)v[q];
#endif
}

// ---------------- graph preprocessing ----------------

__global__ void zero_kernel(int* __restrict__ p, int n) {
    int i = blockIdx.x * blockDim.x + threadIdx.x;
    if (i < n) p[i] = 0;
}

// One pass: LDS bucket histograms (dst+src), per-edge packed ranks,
// per-(bucket,block) count tables (k-major), global bucket totals.
__global__ __launch_bounds__(256) void count_rank_kernel(
        const int* __restrict__ src, const int* __restrict__ dst,
        int* __restrict__ bcnt, int* __restrict__ sbcnt,
        unsigned* __restrict__ rank, int* __restrict__ cntD, int* __restrict__ cntS,
        int K, int E) {
    __shared__ int lc[KMAX], ls[KMAX];
    const int tid = threadIdx.x;
    lc[tid] = 0; lc[tid + 256] = 0; ls[tid] = 0; ls[tid + 256] = 0;
    __syncthreads();
    const int base = blockIdx.x * EPB;
    const int lim = min(EPB, E - base);
    for (int i = tid; i < lim; i += 256) {
        int kd = dst[base + i] >> BSH, ks = src[base + i] >> BSH;
        unsigned rd = (unsigned)atomicAdd(&lc[kd], 1);
        unsigned rs = (unsigned)atomicAdd(&ls[ks], 1);
        rank[base + i] = rd | (rs << 16);
    }
    __syncthreads();
    for (int t = tid; t < K; t += 256) {
        cntD[t * NBMAX + blockIdx.x] = lc[t];
        cntS[t * NBMAX + blockIdx.x] = ls[t];
        if (lc[t]) atomicAdd(&bcnt[t], lc[t]);
        if (ls[t]) atomicAdd(&sbcnt[t], ls[t]);
    }
}

// one wave: exclusive scan of both bucket-total arrays (K <= KMAX)
__global__ void bucket_scan_kernel(const int* __restrict__ a, const int* __restrict__ b,
                                   int* __restrict__ abase, int* __restrict__ bbase, int K) {
    const int lane = threadIdx.x;   // blockDim = 64
    int ca = 0, cb = 0;
    for (int base = 0; base < K; base += 64) {
        int va = (base + lane < K) ? a[base + lane] : 0;
        int vb = (base + lane < K) ? b[base + lane] : 0;
        int ia = va, ib = vb;
        #pragma unroll
        for (int d = 1; d < 64; d <<= 1) {
            int oa = __shfl_up(ia, d, 64);
            int ob = __shfl_up(ib, d, 64);
            if (lane >= d) { ia += oa; ib += ob; }
        }
        if (base + lane < K) { abase[base + lane] = ca + ia - va; bbase[base + lane] = cb + ib - vb; }
        ca += __shfl(ia, 63, 64);
        cb += __shfl(ib, 63, 64);
    }
    if (lane == 0) { abase[K] = ca; bbase[K] = cb; }
}

// grid 2K x 64: convert count tables (k-major) to absolute base tables in place
__global__ void basebk_kernel(const int* __restrict__ bbase, const int* __restrict__ sbase,
                              int* __restrict__ cntD, int* __restrict__ cntS,
                              int K, int NB) {
    const bool isS = (int)blockIdx.x >= K;
    const int k = isS ? (blockIdx.x - K) : blockIdx.x;
    int* tbl = isS ? cntS : cntD;
    int run = isS ? sbase[k] : bbase[k];
    const int lane = threadIdx.x;   // 64
    for (int b0 = 0; b0 < NB; b0 += 64) {
        int v = (b0 + lane < NB) ? tbl[k * NBMAX + b0 + lane] : 0;
        int incl = v;
        #pragma unroll
        for (int d = 1; d < 64; d <<= 1) {
            int o = __shfl_up(incl, d, 64);
            if (lane >= d) incl += o;
        }
        if (b0 + lane < NB) tbl[k * NBMAX + b0 + lane] = run + incl - v;
        run += __shfl(incl, 63, 64);
    }
}

// pure streaming scatter: no LDS counting, no atomics
__global__ __launch_bounds__(256) void scatter_kernel(
        const int* __restrict__ src, const int* __restrict__ dst,
        const unsigned* __restrict__ rank,
        const int* __restrict__ baseD, const int* __restrict__ baseS,
        unsigned* __restrict__ dbuf, int* __restrict__ sbuf, int K, int E) {
    __shared__ int ldsD[KMAX], ldsS[KMAX];
    const int tid = threadIdx.x, b = blockIdx.x;
    for (int t = tid; t < K; t += 256) {
        ldsD[t] = baseD[t * NBMAX + b];
        ldsS[t] = baseS[t * NBMAX + b];
    }
    __syncthreads();
    const int base = b * EPB;
    const int lim = min(EPB, E - base);
    for (int i = tid; i < lim; i += 256) {
        int d = dst[base + i], s = src[base + i];
        unsigned r = rank[base + i];
        dbuf[ldsD[d >> BSH] + (r & 0xFFFFu)] = (unsigned)s | ((unsigned)(d & (BSZ - 1)) << 24);
        sbuf[ldsS[s >> BSH] + (r >> 16)] = s;
    }
}

// fused: blocks [0,K) build CSR; [K,2K) out_norm; [2K,..) weight conversion
__global__ __launch_bounds__(256) void finish_kernel(
        const unsigned* __restrict__ dbuf, const int* __restrict__ sbuf,
        const int* __restrict__ bbase, const int* __restrict__ sbase,
        int* __restrict__ row_ptr, float* __restrict__ in_norm,
        float* __restrict__ out_norm, int* __restrict__ col,
        const float* __restrict__ W1, const float* __restrict__ W2,
        const float* __restrict__ W3, const float* __restrict__ Wp,
        _Float16* __restrict__ WT, _Float16* __restrict__ Wph, _Float16* __restrict__ Wpr,
        int N, int K, int E) {
    __shared__ int cnt[BSZ], lsc[BSZ];
    __shared__ int wsum[4];
    const int blk = blockIdx.x, tid = threadIdx.x;

    if (blk < K) {
        // ---- build CSR for dst-bucket blk ----
        const int k = blk;
        const int node0 = k << BSH;
        const int beg = bbase[k], end = bbase[k + 1];
        cnt[tid] = 0;
        __syncthreads();
        for (int i = beg + tid; i < end; i += 256)
            atomicAdd(&cnt[dbuf[i] >> 24], 1);
        __syncthreads();
        const int c0 = cnt[tid];
        int incl = c0;
        const int lane = tid & 63, w = tid >> 6;
        #pragma unroll
        for (int d = 1; d < 64; d <<= 1) {
            int o = __shfl_up(incl, d, 64);
            if (lane >= d) incl += o;
        }
        if (lane == 63) wsum[w] = incl;
        __syncthreads();
        int off = 0;
        for (int j = 0; j < w; ++j) off += wsum[j];
        const int excl = off + incl - c0;
        lsc[tid] = excl;
        const int node = node0 + tid;
        if (node < N) { row_ptr[node] = beg + excl; in_norm[node] = 1.0f / sqrtf((float)max(c0, 1)); }
        if (k == K - 1 && tid == 0) row_ptr[N] = E;
        __syncthreads();
        cnt[tid] = 0;
        __syncthreads();
        for (int i = beg + tid; i < end; i += 256) {
            unsigned e = dbuf[i];
            int local = e >> 24;
            int r = atomicAdd(&cnt[local], 1);
            col[beg + lsc[local] + r] = (int)(e & 0xFFFFFFu);
        }
    } else if (blk < 2 * K) {
        // ---- out_norm for src-bucket blk-K ----
        const int k = blk - K;
        const int beg = sbase[k], end = sbase[k + 1];
        cnt[tid] = 0;
        __syncthreads();
        for (int i = beg + tid; i < end; i += 256)
            atomicAdd(&cnt[sbuf[i] & (BSZ - 1)], 1);
        __syncthreads();
        const int n0 = (k << BSH) + tid;
        if (n0 < N) out_norm[n0] = 1.0f / sqrtf((float)max(cnt[tid], 1));
    } else {
        // ---- weight conversion ----
        int i = (blk - 2 * K) * 256 + tid;
        if (i < 3 * HDIM * HDIM) {
            int w = i >> 14, r = i & (HDIM * HDIM - 1);
            int nn = r >> 7, kk = r & 127;
            const float* W = (w == 0) ? W1 : (w == 1) ? W2 : W3;
            WT[i] = (_Float16)W[kk * HDIM + nn];
        } else if (i < 3 * HDIM * HDIM + NCLS * HDIM) {
            int j = i - 3 * HDIM * HDIM;
            float v = Wp[j];
            _Float16 hi = (_Float16)v;
            Wph[j] = hi;
            Wpr[j] = (_Float16)(v - (float)hi);
        }
    }
}

// ---------------- dense compute ----------------

// out[m,:] = fp16( (out_norm[m]*x[m,:]) @ W ) via mfma_f32_16x16x32_f16.
// 128-row block, 2 m-tiles/wave; fp16 LDS staging; IT = float (row-major
// input) or _Float16 (sliced input). Output always sliced [8][n][16].
template <typename IT>
__global__ __launch_bounds__(256) void gemm_mfma_kernel(
        const IT* __restrict__ x, const _Float16* __restrict__ WT,
        const float* __restrict__ out_norm, _Float16* __restrict__ out, int n) {
    __shared__ _Float16 xh[128 * 136];          // 34.8 KB; also epilogue cs
    const int tid = threadIdx.x;
    const int wave = tid >> 6, lane = tid & 63;
    const int quad = lane >> 4, cI = lane & 15;
    const int row0 = blockIdx.x * 128;

    for (int t = tid; t < 128 * 16; t += 256) {
        int r = t >> 4, c8 = t & 15;
        int gr = row0 + r;
        half8 hv = {};
        if (gr < n) {
            float sc = out_norm[gr];
            if constexpr (sizeof(IT) == 2) {
                half8 v = *(const half8*)((const _Float16*)x + sl_off(gr, c8, n));
                #pragma unroll
                for (int q = 0; q < 8; ++q) hv[q] = (_Float16)((float)v[q] * sc);
            } else {
                const float* xr = (const float*)x + (size_t)gr * HDIM + c8 * 8;
                float4 u = *(const float4*)xr;
                float4 v = *(const float4*)(xr + 4);
                hv[0] = (_Float16)(u.x * sc); hv[1] = (_Float16)(u.y * sc);
                hv[2] = (_Float16)(u.z * sc); hv[3] = (_Float16)(u.w * sc);
                hv[4] = (_Float16)(v.x * sc); hv[5] = (_Float16)(v.y * sc);
                hv[6] = (_Float16)(v.z * sc); hv[7] = (_Float16)(v.w * sc);
            }
        }
        *(half8*)&xh[r * 136 + c8 * 8] = hv;
    }
    __syncthreads();

    half8 afr[2][4];
    #pragma unroll
    for (int i = 0; i < 2; ++i) {
        int mrow = wave * 32 + i * 16 + cI;
        #pragma unroll
        for (int kc = 0; kc < 4; ++kc)
            afr[i][kc] = *(const half8*)&xh[mrow * 136 + kc * 32 + quad * 8];
    }
    __syncthreads();

    f32x4 acc[2][8];
    #pragma unroll
    for (int i = 0; i < 2; ++i)
        #pragma unroll
        for (int nt = 0; nt < 8; ++nt) acc[i][nt] = (f32x4){0.f, 0.f, 0.f, 0.f};

    #pragma unroll
    for (int nt = 0; nt < 8; ++nt) {
        const _Float16* wb = WT + (size_t)(nt * 16 + cI) * HDIM + quad * 8;
        half8 bfr[4];
        #pragma unroll
        for (int kc = 0; kc < 4; ++kc) bfr[kc] = *(const half8*)(wb + kc * 32);
        #pragma unroll
        for (int i = 0; i < 2; ++i)
            #pragma unroll
            for (int kc = 0; kc < 4; ++kc)
                acc[i][nt] = __builtin_amdgcn_mfma_f32_16x16x32_f16(afr[i][kc], bfr[kc], acc[i][nt], 0, 0, 0);
    }

    _Float16 (*cs)[136] = (_Float16(*)[136])xh;
    #pragma unroll
    for (int i = 0; i < 2; ++i)
        #pragma unroll
        for (int nt = 0; nt < 8; ++nt)
            #pragma unroll
            for (int r = 0; r < 4; ++r)
                cs[wave * 32 + i * 16 + quad * 4 + r][nt * 16 + cI] = (_Float16)acc[i][nt][r];
    __syncthreads();

    for (int t = tid; t < 128 * 16; t += 256) {
        int r = t >> 4, c8 = t & 15;
        int gr = row0 + r;
        if (gr < n)
            *(float4*)(out + sl_off(gr, c8, n)) = *(float4*)&cs[r][c8 * 8];
    }
}

// R17 XCD-sliced gather, max-MLP shape: 2 lanes/node (chunk 0/1); each lane
// walks the node's whole contiguous col list with an 8-deep software
// pipeline (8 rows in flight while next window's 8 cols load). No cross-lane
// reduction. Unguarded full windows (col over-read stays in mapped
// workspace); guarded tail with dummy loads to row 0 (coalesce to ~1 req),
// value-zeroed. slice = blockIdx&7 pins the 3.2 MB slice in one XCD's L2.
__global__ __launch_bounds__(256) void agg_slice_kernel(
        const _Float16* __restrict__ t, const int* __restrict__ row_ptr,
        const int* __restrict__ col, const float* __restrict__ in_norm,
        const float* __restrict__ bias, _Float16* __restrict__ h, int n) {
    const int s = blockIdx.x & 7;           // slice == XCD under round-robin
    const int g = blockIdx.x >> 3;
    const int tid = threadIdx.x;
    const int node = g * 128 + (tid >> 1);
    if (node >= n) return;
    const int chunk = tid & 1;
    const int cofs = chunk * 8;

    const _Float16* __restrict__ ts = t + (size_t)s * (size_t)n * 16;
    const int beg = row_ptr[node], end = row_ptr[node + 1];

    float f[8] = {};
    int e = beg;
    int ca[8];
    #pragma unroll
    for (int i = 0; i < 8; ++i) ca[i] = col[e + i];   // over-read OK (mapped)

    // full 8-edge windows, pipelined: next cols load under current rows
    while (e + 8 <= end) {
        int cb[8];
        #pragma unroll
        for (int i = 0; i < 8; ++i) cb[i] = col[e + 8 + i];
        half8 v[8];
        #pragma unroll
        for (int i = 0; i < 8; ++i)
            v[i] = *(const half8*)(ts + (size_t)ca[i] * 16 + cofs);
        #pragma unroll
        for (int i = 0; i < 8; ++i) accum8(f, v[i]);
        #pragma unroll
        for (int i = 0; i < 8; ++i) ca[i] = cb[i];
        e += 8;
    }
    // tail: 0..7 edges, cols already in ca
    {
        const int w = end - e;
        const half8 z = {};
        half8 v[8];
        #pragma unroll
        for (int i = 0; i < 8; ++i) {
            const int c = (i < w) ? ca[i] : 0;
            half8 tv = *(const half8*)(ts + (size_t)c * 16 + cofs);
            v[i] = (i < w) ? tv : z;
        }
        #pragma unroll
        for (int i = 0; i < 8; ++i) accum8(f, v[i]);
    }

    const float inn = in_norm[node];
    const float* bb = bias + s * 16 + cofs;
    float4 b0 = *(const float4*)bb;
    float4 b1 = *(const float4*)(bb + 4);
    half8 hv;
    hv[0] = (_Float16)fmaxf(f[0] * inn + b0.x, 0.f);
    hv[1] = (_Float16)fmaxf(f[1] * inn + b0.y, 0.f);
    hv[2] = (_Float16)fmaxf(f[2] * inn + b0.z, 0.f);
    hv[3] = (_Float16)fmaxf(f[3] * inn + b0.w, 0.f);
    hv[4] = (_Float16)fmaxf(f[4] * inn + b1.x, 0.f);
    hv[5] = (_Float16)fmaxf(f[5] * inn + b1.y, 0.f);
    hv[6] = (_Float16)fmaxf(f[6] * inn + b1.z, 0.f);
    hv[7] = (_Float16)fmaxf(f[7] * inn + b1.w, 0.f);
    *(half8*)(h + (size_t)s * (size_t)n * 16 + (size_t)node * 16 + cofs) = hv;
}

__global__ void seg_kernel(const float* __restrict__ colsum, const float* __restrict__ Wp,
                           const float* __restrict__ bp, float* __restrict__ segout, float inv_n) {
    int c = threadIdx.x;
    if (c < NCLS) {
        float s = 0.f;
        #pragma unroll 4
        for (int k = 0; k < HDIM; ++k) s = fmaf(colsum[k], Wp[c * HDIM + k], s);
        segout[c] = s * inv_n + bp[c];
    }
}

// CAM via MFMA: CAM[c,n] = dot(Wp[c,:], h3[n,:]). h3 is sliced [8][n][16].
// Block = 128 nodes staged in LDS; per class-tile A load.
__global__ __launch_bounds__(256) void cam_mfma_kernel(
        const _Float16* __restrict__ h, const _Float16* __restrict__ Wph,
        const _Float16* __restrict__ Wpr, float* __restrict__ out,
        float* __restrict__ colsum, int n) {
    __shared__ _Float16 hs[128 * CSTRIDE];      // 35 KB
    const int tid = threadIdx.x;
    const int wave = tid >> 6, lane = tid & 63;
    const int quad = lane >> 4, cI = lane & 15;
    const int n0 = blockIdx.x * 128;

    for (int t = tid; t < 128 * 16; t += 256) {
        int r = t >> 4, c8 = t & 15;
        int gr = n0 + r;
        half8 v = {};
        if (gr < n) v = *(const half8*)(h + sl_off(gr, c8, n));
        *(half8*)&hs[r * CSTRIDE + c8 * 8] = v;
    }
    __syncthreads();

    #pragma unroll
    for (int ct = 0; ct < 3; ++ct) {
        const int cls = ct * 16 + cI;
        const bool av = cls < NCLS;
        const int clc = av ? cls : 0;
        half8 ah[4], ar[4];
        #pragma unroll
        for (int kc = 0; kc < 4; ++kc) {
            half8 z = {};
            half8 vh = *(const half8*)(Wph + clc * HDIM + kc * 32 + quad * 8);
            half8 vr = *(const half8*)(Wpr + clc * HDIM + kc * 32 + quad * 8);
            ah[kc] = av ? vh : z;
            ar[kc] = av ? vr : z;
        }
        #pragma unroll
        for (int t = 0; t < 2; ++t) {
            const int ln = wave * 32 + t * 16 + cI;
            f32x4 acc = (f32x4){0.f, 0.f, 0.f, 0.f};
            #pragma unroll
            for (int kc = 0; kc < 4; ++kc) {
                half8 b = *(const half8*)&hs[ln * CSTRIDE + kc * 32 + quad * 8];
                acc = __builtin_amdgcn_mfma_f32_16x16x32_f16(ah[kc], b, acc, 0, 0, 0);
                acc = __builtin_amdgcn_mfma_f32_16x16x32_f16(ar[kc], b, acc, 0, 0, 0);
            }
            const int node = n0 + ln;
            #pragma unroll
            for (int r = 0; r < 4; ++r) {
                int c2 = ct * 16 + quad * 4 + r;
                if (c2 < NCLS && node < n)
                    out[(size_t)c2 * n + node] = acc[r];
            }
        }
    }

    if (tid < HDIM) {
        float s = 0.f;
        for (int r = 0; r < 128; ++r) s += (float)hs[r * CSTRIDE + tid];
        atomicAdd(&colsum[tid], s);
    }
}

// ---------------- launch ----------------

extern "C" void kernel_launch(void* const* d_in, const int* in_sizes, int n_in,
                              void* d_out, int out_size, void* d_ws, size_t ws_size,
                              hipStream_t stream) {
    const float* features = (const float*)d_in[0];
    const float* W1 = (const float*)d_in[1];
    const float* b1 = (const float*)d_in[2];
    const float* W2 = (const float*)d_in[3];
    const float* b2 = (const float*)d_in[4];
    const float* W3 = (const float*)d_in[5];
    const float* b3 = (const float*)d_in[6];
    const float* Wp = (const float*)d_in[7];
    const float* bp = (const float*)d_in[8];
    const int*   src = (const int*)d_in[9];
    const int*   dst = (const int*)d_in[10];

    const int N = in_sizes[0] / HDIM;
    const int E = in_sizes[9];
    const int K = (N + BSZ - 1) >> BSH;           // buckets (<= KMAX)
    const int NB = (E + EPB - 1) / EPB;           // <= NBMAX
    float* out = (float*)d_out;

    // workspace carve-up
    char* ws = (char*)d_ws;
    size_t off = 0;
    int* bcnt   = (int*)(ws + off); off += KMAX * 4;
    int* sbcnt  = (int*)(ws + off); off += KMAX * 4;
    float* colsum = (float*)(ws + off); off += 128 * 4;
    int* bbase  = (int*)(ws + off); off += (KMAX + 1) * 4;
    int* sbase  = (int*)(ws + off); off += (KMAX + 1) * 4;
    int* cntD   = (int*)(ws + off); off += (size_t)KMAX * NBMAX * 4;   // -> baseD
    int* cntS   = (int*)(ws + off); off += (size_t)KMAX * NBMAX * 4;   // -> baseS
    int* row_ptr = (int*)(ws + off); off += ((size_t)N + 1) * 4; off = (off + 15) & ~(size_t)15;
    int* col_idx = (int*)(ws + off); off += (size_t)E * 4; off = (off + 15) & ~(size_t)15;
    float* out_norm = (float*)(ws + off); off += (size_t)N * 4;
    float* in_norm  = (float*)(ws + off); off += (size_t)N * 4; off = (off + 255) & ~(size_t)255;
    _Float16* WT  = (_Float16*)(ws + off); off += 3 * HDIM * HDIM * 2;
    _Float16* Wph = (_Float16*)(ws + off); off += NCLS * HDIM * 2;
    _Float16* Wpr = (_Float16*)(ws + off); off += NCLS * HDIM * 2; off = (off + 255) & ~(size_t)255;
    _Float16* Bh  = (_Float16*)(ws + off); off += (size_t)N * HDIM * 2; off = (off + 255) & ~(size_t)255;
    _Float16* F0h = (_Float16*)(ws + off); off += (size_t)N * HDIM * 2; off = (off + 255) & ~(size_t)255;
    (void)ws_size; (void)n_in; (void)out_size;

    // aliases: rank in Bh (first written by gemm1); dbuf/sbuf in F0h (first
    // written by agg1, after finish_kernel consumed them)
    unsigned* rank = (unsigned*)Bh;                   // E*4 B
    unsigned* dbuf = (unsigned*)F0h;                  // E*4 B (packed src|local<<24)
    int*      sbuf = (int*)((char*)F0h + (size_t)E * 4);  // E*4 B

    const int nzero = 2 * KMAX + 128;
    zero_kernel<<<(nzero + 255) / 256, 256, 0, stream>>>((int*)ws, nzero);
    count_rank_kernel<<<NB, 256, 0, stream>>>(src, dst, bcnt, sbcnt, rank, cntD, cntS, K, E);
    bucket_scan_kernel<<<1, 64, 0, stream>>>(bcnt, sbcnt, bbase, sbase, K);
    basebk_kernel<<<2 * K, 64, 0, stream>>>(bbase, sbase, cntD, cntS, K, NB);
    scatter_kernel<<<NB, 256, 0, stream>>>(src, dst, rank, cntD, cntS, dbuf, sbuf, K, E);

    const int conv_blocks = (3 * HDIM * HDIM + NCLS * HDIM + 255) / 256;
    finish_kernel<<<2 * K + conv_blocks, 256, 0, stream>>>(
        dbuf, sbuf, bbase, sbase, row_ptr, in_norm, out_norm, col_idx,
        W1, W2, W3, Wp, WT, Wph, Wpr, N, K, E);

    const int gemm_blocks = (N + 127) / 128;
    const int agg_blocks  = ((N + 127) / 128) * 8;   // node-groups x 8 slices

    // layer 1
    gemm_mfma_kernel<float><<<gemm_blocks, 256, 0, stream>>>(features, WT, out_norm, Bh, N);
    agg_slice_kernel<<<agg_blocks, 256, 0, stream>>>(Bh, row_ptr, col_idx, in_norm, b1, F0h, N);
    // layer 2
    gemm_mfma_kernel<_Float16><<<gemm_blocks, 256, 0, stream>>>(F0h, WT + HDIM * HDIM, out_norm, Bh, N);
    agg_slice_kernel<<<agg_blocks, 256, 0, stream>>>(Bh, row_ptr, col_idx, in_norm, b2, F0h, N);
    // layer 3 (h3 sliced fp16 -> F0h)
    gemm_mfma_kernel<_Float16><<<gemm_blocks, 256, 0, stream>>>(F0h, WT + 2 * HDIM * HDIM, out_norm, Bh, N);
    agg_slice_kernel<<<agg_blocks, 256, 0, stream>>>(Bh, row_ptr, col_idx, in_norm, b3, F0h, N);

    // head: cam (MFMA, fused colsum) then seg
    cam_mfma_kernel<<<(N + 127) / 128, 256, 0, stream>>>(F0h, Wph, Wpr, out + NCLS, colsum, N);
    seg_kernel<<<1, 64, 0, stream>>>(colsum, Wp, bp, out, 1.0f / (float)N);
}

// Round 6
// 462.587 us; speedup vs baseline: 1.1777x; 1.0925x over previous
//
#include <hip/hip_runtime.h>
#include <hip/hip_bf16.h>
#include <hip/hip_fp16.h>

// GCN: 3 layers of  h = relu(in_norm * A_pull( (out_norm*x) @ W ) + b)
// then seg_output = (mean_n h3) @ Wp^T + bp  and  CAM = Wp @ h3^T.
// Preprocessing (R12): one count+rank pass (LDS bucket histograms,
// per-edge packed ranks), base-table scans, pure-streaming scatter (4B packed
// dst-records), fused csr+outdeg+convw. No scattered global atomics.
// R13-R17 lesson: XCD-sliced [8][N][16] layout cut L3 fill 180->44 MB but hit
// a scattered-request service wall (~74 us/layer, per-CU L1-miss tracking x
// L2 latency); full-row gathers are line-efficient and faster (59 us/layer,
// at the ~3.5 TB/s L3->L2 random 256B-row fill ceiling). REVERTED to
// row-major.
// R18: agg accumulate via v_dot2_f32_f16 (8 VALU per 16B chunk vs 12 for
// cvt+add; exact) — R12's agg was VALU-co-limited (VALUBusy 70%).
// All h tensors fp16. CAM = MFMA GEMM (split-fp16 Wp, exact).

#define HDIM 128
#define NCLS 40
#define BSH 8
#define BSZ 256          // nodes per bucket
#define KMAX 512
#define NBMAX 512
#define EPB 4096         // edges per count/scatter block
#define CSTRIDE 140      // cam LDS row stride (fp16)

typedef _Float16 half8 __attribute__((ext_vector_type(8)));
typedef _Float16 half2t __attribute__((ext_vector_type(2)));
typedef float f32x4 __attribute__((ext_vector_type(4)));

// ---------------- graph preprocessing ----------------

__global__ void zero_kernel(int* __restrict__ p, int n) {
    int i = blockIdx.x * blockDim.x + threadIdx.x;
    if (i < n) p[i] = 0;
}

// One pass: LDS bucket histograms (dst+src), per-edge packed ranks,
// per-(bucket,block) count tables (k-major), global bucket totals.
__global__ __launch_bounds__(256) void count_rank_kernel(
        const int* __restrict__ src, const int* __restrict__ dst,
        int* __restrict__ bcnt, int* __restrict__ sbcnt,
        unsigned* __restrict__ rank, int* __restrict__ cntD, int* __restrict__ cntS,
        int K, int E) {
    __shared__ int lc[KMAX], ls[KMAX];
    const int tid = threadIdx.x;
    lc[tid] = 0; lc[tid + 256] = 0; ls[tid] = 0; ls[tid + 256] = 0;
    __syncthreads();
    const int base = blockIdx.x * EPB;
    const int lim = min(EPB, E - base);
    for (int i = tid; i < lim; i += 256) {
        int kd = dst[base + i] >> BSH, ks = src[base + i] >> BSH;
        unsigned rd = (unsigned)atomicAdd(&lc[kd], 1);
        unsigned rs = (unsigned)atomicAdd(&ls[ks], 1);
        rank[base + i] = rd | (rs << 16);
    }
    __syncthreads();
    for (int t = tid; t < K; t += 256) {
        cntD[t * NBMAX + blockIdx.x] = lc[t];
        cntS[t * NBMAX + blockIdx.x] = ls[t];
        if (lc[t]) atomicAdd(&bcnt[t], lc[t]);
        if (ls[t]) atomicAdd(&sbcnt[t], ls[t]);
    }
}

// one wave: exclusive scan of both bucket-total arrays (K <= KMAX)
__global__ void bucket_scan_kernel(const int* __restrict__ a, const int* __restrict__ b,
                                   int* __restrict__ abase, int* __restrict__ bbase, int K) {
    const int lane = threadIdx.x;   // blockDim = 64
    int ca = 0, cb = 0;
    for (int base = 0; base < K; base += 64) {
        int va = (base + lane < K) ? a[base + lane] : 0;
        int vb = (base + lane < K) ? b[base + lane] : 0;
        int ia = va, ib = vb;
        #pragma unroll
        for (int d = 1; d < 64; d <<= 1) {
            int oa = __shfl_up(ia, d, 64);
            int ob = __shfl_up(ib, d, 64);
            if (lane >= d) { ia += oa; ib += ob; }
        }
        if (base + lane < K) { abase[base + lane] = ca + ia - va; bbase[base + lane] = cb + ib - vb; }
        ca += __shfl(ia, 63, 64);
        cb += __shfl(ib, 63, 64);
    }
    if (lane == 0) { abase[K] = ca; bbase[K] = cb; }
}

// grid 2K x 64: convert count tables (k-major) to absolute base tables in place
__global__ void basebk_kernel(const int* __restrict__ bbase, const int* __restrict__ sbase,
                              int* __restrict__ cntD, int* __restrict__ cntS,
                              int K, int NB) {
    const bool isS = (int)blockIdx.x >= K;
    const int k = isS ? (blockIdx.x - K) : blockIdx.x;
    int* tbl = isS ? cntS : cntD;
    int run = isS ? sbase[k] : bbase[k];
    const int lane = threadIdx.x;   // 64
    for (int b0 = 0; b0 < NB; b0 += 64) {
        int v = (b0 + lane < NB) ? tbl[k * NBMAX + b0 + lane] : 0;
        int incl = v;
        #pragma unroll
        for (int d = 1; d < 64; d <<= 1) {
            int o = __shfl_up(incl, d, 64);
            if (lane >= d) incl += o;
        }
        if (b0 + lane < NB) tbl[k * NBMAX + b0 + lane] = run + incl - v;
        run += __shfl(incl, 63, 64);
    }
}

// pure streaming scatter: no LDS counting, no atomics
__global__ __launch_bounds__(256) void scatter_kernel(
        const int* __restrict__ src, const int* __restrict__ dst,
        const unsigned* __restrict__ rank,
        const int* __restrict__ baseD, const int* __restrict__ baseS,
        unsigned* __restrict__ dbuf, int* __restrict__ sbuf, int K, int E) {
    __shared__ int ldsD[KMAX], ldsS[KMAX];
    const int tid = threadIdx.x, b = blockIdx.x;
    for (int t = tid; t < K; t += 256) {
        ldsD[t] = baseD[t * NBMAX + b];
        ldsS[t] = baseS[t * NBMAX + b];
    }
    __syncthreads();
    const int base = b * EPB;
    const int lim = min(EPB, E - base);
    for (int i = tid; i < lim; i += 256) {
        int d = dst[base + i], s = src[base + i];
        unsigned r = rank[base + i];
        dbuf[ldsD[d >> BSH] + (r & 0xFFFFu)] = (unsigned)s | ((unsigned)(d & (BSZ - 1)) << 24);
        sbuf[ldsS[s >> BSH] + (r >> 16)] = s;
    }
}

// fused: blocks [0,K) build CSR; [K,2K) out_norm; [2K,..) weight conversion
__global__ __launch_bounds__(256) void finish_kernel(
        const unsigned* __restrict__ dbuf, const int* __restrict__ sbuf,
        const int* __restrict__ bbase, const int* __restrict__ sbase,
        int* __restrict__ row_ptr, float* __restrict__ in_norm,
        float* __restrict__ out_norm, int* __restrict__ col,
        const float* __restrict__ W1, const float* __restrict__ W2,
        const float* __restrict__ W3, const float* __restrict__ Wp,
        _Float16* __restrict__ WT, _Float16* __restrict__ Wph, _Float16* __restrict__ Wpr,
        int N, int K, int E) {
    __shared__ int cnt[BSZ], lsc[BSZ];
    __shared__ int wsum[4];
    const int blk = blockIdx.x, tid = threadIdx.x;

    if (blk < K) {
        // ---- build CSR for dst-bucket blk ----
        const int k = blk;
        const int node0 = k << BSH;
        const int beg = bbase[k], end = bbase[k + 1];
        cnt[tid] = 0;
        __syncthreads();
        for (int i = beg + tid; i < end; i += 256)
            atomicAdd(&cnt[dbuf[i] >> 24], 1);
        __syncthreads();
        const int c0 = cnt[tid];
        int incl = c0;
        const int lane = tid & 63, w = tid >> 6;
        #pragma unroll
        for (int d = 1; d < 64; d <<= 1) {
            int o = __shfl_up(incl, d, 64);
            if (lane >= d) incl += o;
        }
        if (lane == 63) wsum[w] = incl;
        __syncthreads();
        int off = 0;
        for (int j = 0; j < w; ++j) off += wsum[j];
        const int excl = off + incl - c0;
        lsc[tid] = excl;
        const int node = node0 + tid;
        if (node < N) { row_ptr[node] = beg + excl; in_norm[node] = 1.0f / sqrtf((float)max(c0, 1)); }
        if (k == K - 1 && tid == 0) row_ptr[N] = E;
        __syncthreads();
        cnt[tid] = 0;
        __syncthreads();
        for (int i = beg + tid; i < end; i += 256) {
            unsigned e = dbuf[i];
            int local = e >> 24;
            int r = atomicAdd(&cnt[local], 1);
            col[beg + lsc[local] + r] = (int)(e & 0xFFFFFFu);
        }
    } else if (blk < 2 * K) {
        // ---- out_norm for src-bucket blk-K ----
        const int k = blk - K;
        const int beg = sbase[k], end = sbase[k + 1];
        cnt[tid] = 0;
        __syncthreads();
        for (int i = beg + tid; i < end; i += 256)
            atomicAdd(&cnt[sbuf[i] & (BSZ - 1)], 1);
        __syncthreads();
        const int n0 = (k << BSH) + tid;
        if (n0 < N) out_norm[n0] = 1.0f / sqrtf((float)max(cnt[tid], 1));
    } else {
        // ---- weight conversion ----
        int i = (blk - 2 * K) * 256 + tid;
        if (i < 3 * HDIM * HDIM) {
            int w = i >> 14, r = i & (HDIM * HDIM - 1);
            int nn = r >> 7, kk = r & 127;
            const float* W = (w == 0) ? W1 : (w == 1) ? W2 : W3;
            WT[i] = (_Float16)W[kk * HDIM + nn];
        } else if (i < 3 * HDIM * HDIM + NCLS * HDIM) {
            int j = i - 3 * HDIM * HDIM;
            float v = Wp[j];
            _Float16 hi = (_Float16)v;
            Wph[j] = hi;
            Wpr[j] = (_Float16)(v - (float)hi);
        }
    }
}

// ---------------- dense compute ----------------

// out[m,:] = fp16( (out_norm[m]*x[m,:]) @ W ) via mfma_f32_16x16x32_f16.
// 128-row block, 2 m-tiles/wave; fp16 LDS staging; IT = float or _Float16.
template <typename IT>
__global__ __launch_bounds__(256) void gemm_mfma_kernel(
        const IT* __restrict__ x, const _Float16* __restrict__ WT,
        const float* __restrict__ out_norm, _Float16* __restrict__ out, int n) {
    __shared__ _Float16 xh[128 * 136];          // 34.8 KB; also epilogue cs
    const int tid = threadIdx.x;
    const int wave = tid >> 6, lane = tid & 63;
    const int quad = lane >> 4, cI = lane & 15;
    const int row0 = blockIdx.x * 128;

    for (int t = tid; t < 128 * 16; t += 256) {
        int r = t >> 4, c8 = t & 15;
        int gr = row0 + r;
        half8 hv = {};
        if (gr < n) {
            float sc = out_norm[gr];
            if constexpr (sizeof(IT) == 2) {
                half8 v = *(const half8*)((const _Float16*)x + (size_t)gr * HDIM + c8 * 8);
                #pragma unroll
                for (int q = 0; q < 8; ++q) hv[q] = (_Float16)((float)v[q] * sc);
            } else {
                const float* xr = (const float*)x + (size_t)gr * HDIM + c8 * 8;
                float4 u = *(const float4*)xr;
                float4 v = *(const float4*)(xr + 4);
                hv[0] = (_Float16)(u.x * sc); hv[1] = (_Float16)(u.y * sc);
                hv[2] = (_Float16)(u.z * sc); hv[3] = (_Float16)(u.w * sc);
                hv[4] = (_Float16)(v.x * sc); hv[5] = (_Float16)(v.y * sc);
                hv[6] = (_Float16)(v.z * sc); hv[7] = (_Float16)(v.w * sc);
            }
        }
        *(half8*)&xh[r * 136 + c8 * 8] = hv;
    }
    __syncthreads();

    half8 afr[2][4];
    #pragma unroll
    for (int i = 0; i < 2; ++i) {
        int mrow = wave * 32 + i * 16 + cI;
        #pragma unroll
        for (int kc = 0; kc < 4; ++kc)
            afr[i][kc] = *(const half8*)&xh[mrow * 136 + kc * 32 + quad * 8];
    }
    __syncthreads();

    f32x4 acc[2][8];
    #pragma unroll
    for (int i = 0; i < 2; ++i)
        #pragma unroll
        for (int nt = 0; nt < 8; ++nt) acc[i][nt] = (f32x4){0.f, 0.f, 0.f, 0.f};

    #pragma unroll
    for (int nt = 0; nt < 8; ++nt) {
        const _Float16* wb = WT + (size_t)(nt * 16 + cI) * HDIM + quad * 8;
        half8 bfr[4];
        #pragma unroll
        for (int kc = 0; kc < 4; ++kc) bfr[kc] = *(const half8*)(wb + kc * 32);
        #pragma unroll
        for (int i = 0; i < 2; ++i)
            #pragma unroll
            for (int kc = 0; kc < 4; ++kc)
                acc[i][nt] = __builtin_amdgcn_mfma_f32_16x16x32_f16(afr[i][kc], bfr[kc], acc[i][nt], 0, 0, 0);
    }

    _Float16 (*cs)[136] = (_Float16(*)[136])xh;
    #pragma unroll
    for (int i = 0; i < 2; ++i)
        #pragma unroll
        for (int nt = 0; nt < 8; ++nt)
            #pragma unroll
            for (int r = 0; r < 4; ++r)
                cs[wave * 32 + i * 16 + quad * 4 + r][nt * 16 + cI] = (_Float16)acc[i][nt][r];
    __syncthreads();

    for (int t = tid; t < 128 * 16; t += 256) {
        int r = t >> 4, c8 = t & 15;
        int gr = row0 + r;
        if (gr < n)
            *(float4*)(out + (size_t)gr * HDIM + c8 * 8) = *(float4*)&cs[r][c8 * 8];
    }
}

// accumulate one 16-B fp16 chunk into 8 fp32 sums.
// R18: v_dot2_f32_f16 — 8 VALU per 16 B (vs cvt+add 12), exact.
__device__ __forceinline__ void acc16(const float4& r, float* f) {
#if __has_builtin(__builtin_amdgcn_fdot2)
    const half2t* p = (const half2t*)&r;
    const half2t m0 = {(_Float16)1.0f, (_Float16)0.0f};
    const half2t m1 = {(_Float16)0.0f, (_Float16)1.0f};
    f[0] = __builtin_amdgcn_fdot2(p[0], m0, f[0], false);
    f[1] = __builtin_amdgcn_fdot2(p[0], m1, f[1], false);
    f[2] = __builtin_amdgcn_fdot2(p[1], m0, f[2], false);
    f[3] = __builtin_amdgcn_fdot2(p[1], m1, f[3], false);
    f[4] = __builtin_amdgcn_fdot2(p[2], m0, f[4], false);
    f[5] = __builtin_amdgcn_fdot2(p[2], m1, f[5], false);
    f[6] = __builtin_amdgcn_fdot2(p[3], m0, f[6], false);
    f[7] = __builtin_amdgcn_fdot2(p[3], m1, f[7], false);
#else
    const __half2* p = (const __half2*)&r;
    #pragma unroll
    for (int q = 0; q < 4; ++q) {
        float2 g = __half22float2(p[q]);
        f[2 * q]     += g.x;
        f[2 * q + 1] += g.y;
    }
#endif
}

// fp16 gather: h[n,:] = relu(in_norm[n]*sum t[col[e],:] + b) — one wave/node,
// 16-lane groups x 4 edges in flight. Output fp16. Full 256-B rows: line-
// efficient coalesced gather (L3 random-fill floor ~59 us/layer).
__global__ __launch_bounds__(256) void agg_h_kernel(
        const _Float16* __restrict__ t, const int* __restrict__ row_ptr,
        const int* __restrict__ col, const float* __restrict__ in_norm,
        const float* __restrict__ bias, _Float16* __restrict__ h, int n) {
    int node = blockIdx.x * 4 + (threadIdx.x >> 6);
    if (node >= n) return;
    const int lane = threadIdx.x & 63;
    const int eg = lane >> 4;       // edge group 0..3
    const int fq = lane & 15;       // 16-B feature chunk
    const int beg = row_ptr[node], end = row_ptr[node + 1];
    float f0[8] = {}, f1[8] = {}, f2[8] = {}, f3[8] = {};
    for (int e = beg; e < end; e += 64) {
        int cnt = min(64, end - e);
        int ci = (lane < cnt) ? col[e + lane] : 0;
        for (int j = 0; j < cnt; j += 16) {
            int s0 = __shfl(ci, j + eg, 64);
            int s1 = __shfl(ci, j + 4 + eg, 64);
            int s2 = __shfl(ci, j + 8 + eg, 64);
            int s3 = __shfl(ci, j + 12 + eg, 64);
            float4 r0 = {0.f,0.f,0.f,0.f}, r1 = {0.f,0.f,0.f,0.f};
            float4 r2 = {0.f,0.f,0.f,0.f}, r3 = {0.f,0.f,0.f,0.f};
            if (j + eg < cnt)      r0 = ((const float4*)(t + (size_t)s0 * HDIM))[fq];
            if (j + 4 + eg < cnt)  r1 = ((const float4*)(t + (size_t)s1 * HDIM))[fq];
            if (j + 8 + eg < cnt)  r2 = ((const float4*)(t + (size_t)s2 * HDIM))[fq];
            if (j + 12 + eg < cnt) r3 = ((const float4*)(t + (size_t)s3 * HDIM))[fq];
            acc16(r0, f0);
            acc16(r1, f1);
            acc16(r2, f2);
            acc16(r3, f3);
        }
    }
    float f[8];
    #pragma unroll
    for (int q = 0; q < 8; ++q) f[q] = (f0[q] + f1[q]) + (f2[q] + f3[q]);
    #pragma unroll
    for (int q = 0; q < 8; ++q) f[q] += __shfl_xor(f[q], 16, 64);
    #pragma unroll
    for (int q = 0; q < 8; ++q) f[q] += __shfl_xor(f[q], 32, 64);
    if (eg == 0) {
        float inn = in_norm[node];
        float4 b0 = ((const float4*)bias)[2 * fq];
        float4 b1 = ((const float4*)bias)[2 * fq + 1];
        half8 hv;
        hv[0] = (_Float16)fmaxf(f[0] * inn + b0.x, 0.f);
        hv[1] = (_Float16)fmaxf(f[1] * inn + b0.y, 0.f);
        hv[2] = (_Float16)fmaxf(f[2] * inn + b0.z, 0.f);
        hv[3] = (_Float16)fmaxf(f[3] * inn + b0.w, 0.f);
        hv[4] = (_Float16)fmaxf(f[4] * inn + b1.x, 0.f);
        hv[5] = (_Float16)fmaxf(f[5] * inn + b1.y, 0.f);
        hv[6] = (_Float16)fmaxf(f[6] * inn + b1.z, 0.f);
        hv[7] = (_Float16)fmaxf(f[7] * inn + b1.w, 0.f);
        *(half8*)(h + (size_t)node * HDIM + fq * 8) = hv;
    }
}

__global__ void seg_kernel(const float* __restrict__ colsum, const float* __restrict__ Wp,
                           const float* __restrict__ bp, float* __restrict__ segout, float inv_n) {
    int c = threadIdx.x;
    if (c < NCLS) {
        float s = 0.f;
        #pragma unroll 4
        for (int k = 0; k < HDIM; ++k) s = fmaf(colsum[k], Wp[c * HDIM + k], s);
        segout[c] = s * inv_n + bp[c];
    }
}

// CAM via MFMA: CAM[c,n] = dot(Wp[c,:], h3[n,:]).
// Block = 128 nodes staged in LDS; per class-tile A load (~60 live VGPRs).
__global__ __launch_bounds__(256) void cam_mfma_kernel(
        const _Float16* __restrict__ h, const _Float16* __restrict__ Wph,
        const _Float16* __restrict__ Wpr, float* __restrict__ out,
        float* __restrict__ colsum, int n) {
    __shared__ _Float16 hs[128 * CSTRIDE];      // 35 KB
    const int tid = threadIdx.x;
    const int wave = tid >> 6, lane = tid & 63;
    const int quad = lane >> 4, cI = lane & 15;
    const int n0 = blockIdx.x * 128;

    for (int t = tid; t < 128 * 16; t += 256) {
        int r = t >> 4, c8 = t & 15;
        int gr = n0 + r;
        half8 v = {};
        if (gr < n) v = *(const half8*)(h + (size_t)gr * HDIM + c8 * 8);
        *(half8*)&hs[r * CSTRIDE + c8 * 8] = v;
    }
    __syncthreads();

    #pragma unroll
    for (int ct = 0; ct < 3; ++ct) {
        const int cls = ct * 16 + cI;
        const bool av = cls < NCLS;
        const int clc = av ? cls : 0;
        half8 ah[4], ar[4];
        #pragma unroll
        for (int kc = 0; kc < 4; ++kc) {
            half8 z = {};
            half8 vh = *(const half8*)(Wph + clc * HDIM + kc * 32 + quad * 8);
            half8 vr = *(const half8*)(Wpr + clc * HDIM + kc * 32 + quad * 8);
            ah[kc] = av ? vh : z;
            ar[kc] = av ? vr : z;
        }
        #pragma unroll
        for (int t = 0; t < 2; ++t) {
            const int ln = wave * 32 + t * 16 + cI;
            f32x4 acc = (f32x4){0.f, 0.f, 0.f, 0.f};
            #pragma unroll
            for (int kc = 0; kc < 4; ++kc) {
                half8 b = *(const half8*)&hs[ln * CSTRIDE + kc * 32 + quad * 8];
                acc = __builtin_amdgcn_mfma_f32_16x16x32_f16(ah[kc], b, acc, 0, 0, 0);
                acc = __builtin_amdgcn_mfma_f32_16x16x32_f16(ar[kc], b, acc, 0, 0, 0);
            }
            const int node = n0 + ln;
            #pragma unroll
            for (int r = 0; r < 4; ++r) {
                int c2 = ct * 16 + quad * 4 + r;
                if (c2 < NCLS && node < n)
                    out[(size_t)c2 * n + node] = acc[r];
            }
        }
    }

    if (tid < HDIM) {
        float s = 0.f;
        for (int r = 0; r < 128; ++r) s += (float)hs[r * CSTRIDE + tid];
        atomicAdd(&colsum[tid], s);
    }
}

// ---------------- launch ----------------

extern "C" void kernel_launch(void* const* d_in, const int* in_sizes, int n_in,
                              void* d_out, int out_size, void* d_ws, size_t ws_size,
                              hipStream_t stream) {
    const float* features = (const float*)d_in[0];
    const float* W1 = (const float*)d_in[1];
    const float* b1 = (const float*)d_in[2];
    const float* W2 = (const float*)d_in[3];
    const float* b2 = (const float*)d_in[4];
    const float* W3 = (const float*)d_in[5];
    const float* b3 = (const float*)d_in[6];
    const float* Wp = (const float*)d_in[7];
    const float* bp = (const float*)d_in[8];
    const int*   src = (const int*)d_in[9];
    const int*   dst = (const int*)d_in[10];

    const int N = in_sizes[0] / HDIM;
    const int E = in_sizes[9];
    const int K = (N + BSZ - 1) >> BSH;           // buckets (<= KMAX)
    const int NB = (E + EPB - 1) / EPB;           // <= NBMAX
    float* out = (float*)d_out;

    // workspace carve-up
    char* ws = (char*)d_ws;
    size_t off = 0;
    int* bcnt   = (int*)(ws + off); off += KMAX * 4;
    int* sbcnt  = (int*)(ws + off); off += KMAX * 4;
    float* colsum = (float*)(ws + off); off += 128 * 4;
    int* bbase  = (int*)(ws + off); off += (KMAX + 1) * 4;
    int* sbase  = (int*)(ws + off); off += (KMAX + 1) * 4;
    int* cntD   = (int*)(ws + off); off += (size_t)KMAX * NBMAX * 4;   // -> baseD
    int* cntS   = (int*)(ws + off); off += (size_t)KMAX * NBMAX * 4;   // -> baseS
    int* row_ptr = (int*)(ws + off); off += ((size_t)N + 1) * 4; off = (off + 15) & ~(size_t)15;
    int* col_idx = (int*)(ws + off); off += (size_t)E * 4; off = (off + 15) & ~(size_t)15;
    float* out_norm = (float*)(ws + off); off += (size_t)N * 4;
    float* in_norm  = (float*)(ws + off); off += (size_t)N * 4; off = (off + 255) & ~(size_t)255;
    _Float16* WT  = (_Float16*)(ws + off); off += 3 * HDIM * HDIM * 2;
    _Float16* Wph = (_Float16*)(ws + off); off += NCLS * HDIM * 2;
    _Float16* Wpr = (_Float16*)(ws + off); off += NCLS * HDIM * 2; off = (off + 255) & ~(size_t)255;
    _Float16* Bh  = (_Float16*)(ws + off); off += (size_t)N * HDIM * 2; off = (off + 255) & ~(size_t)255;
    _Float16* F0h = (_Float16*)(ws + off); off += (size_t)N * HDIM * 2; off = (off + 255) & ~(size_t)255;
    (void)ws_size; (void)n_in; (void)out_size;

    // aliases: rank in Bh (first written by gemm1); dbuf/sbuf in F0h (first
    // written by agg1, after finish_kernel consumed them)
    unsigned* rank = (unsigned*)Bh;                   // E*4 B
    unsigned* dbuf = (unsigned*)F0h;                  // E*4 B (packed src|local<<24)
    int*      sbuf = (int*)((char*)F0h + (size_t)E * 4);  // E*4 B

    const int nzero = 2 * KMAX + 128;
    zero_kernel<<<(nzero + 255) / 256, 256, 0, stream>>>((int*)ws, nzero);
    count_rank_kernel<<<NB, 256, 0, stream>>>(src, dst, bcnt, sbcnt, rank, cntD, cntS, K, E);
    bucket_scan_kernel<<<1, 64, 0, stream>>>(bcnt, sbcnt, bbase, sbase, K);
    basebk_kernel<<<2 * K, 64, 0, stream>>>(bbase, sbase, cntD, cntS, K, NB);
    scatter_kernel<<<NB, 256, 0, stream>>>(src, dst, rank, cntD, cntS, dbuf, sbuf, K, E);

    const int conv_blocks = (3 * HDIM * HDIM + NCLS * HDIM + 255) / 256;
    finish_kernel<<<2 * K + conv_blocks, 256, 0, stream>>>(
        dbuf, sbuf, bbase, sbase, row_ptr, in_norm, out_norm, col_idx,
        W1, W2, W3, Wp, WT, Wph, Wpr, N, K, E);

    const int gemm_blocks = (N + 127) / 128;
    const int agg_blocks  = (N + 3) / 4;

    // layer 1
    gemm_mfma_kernel<float><<<gemm_blocks, 256, 0, stream>>>(features, WT, out_norm, Bh, N);
    agg_h_kernel<<<agg_blocks, 256, 0, stream>>>(Bh, row_ptr, col_idx, in_norm, b1, F0h, N);
    // layer 2
    gemm_mfma_kernel<_Float16><<<gemm_blocks, 256, 0, stream>>>(F0h, WT + HDIM * HDIM, out_norm, Bh, N);
    agg_h_kernel<<<agg_blocks, 256, 0, stream>>>(Bh, row_ptr, col_idx, in_norm, b2, F0h, N);
    // layer 3 (h3 fp16 -> F0h)
    gemm_mfma_kernel<_Float16><<<gemm_blocks, 256, 0, stream>>>(F0h, WT + 2 * HDIM * HDIM, out_norm, Bh, N);
    agg_h_kernel<<<agg_blocks, 256, 0, stream>>>(Bh, row_ptr, col_idx, in_norm, b3, F0h, N);

    // head: cam (MFMA, fused colsum) then seg
    cam_mfma_kernel<<<(N + 127) / 128, 256, 0, stream>>>(F0h, Wph, Wpr, out + NCLS, colsum, N);
    seg_kernel<<<1, 64, 0, stream>>>(colsum, Wp, bp, out, 1.0f / (float)N);
}